// Round 7
// baseline (5679.050 us; speedup 1.0000x reference)
//
#include <hip/hip_runtime.h>
#include <hip/hip_bf16.h>
#include <math.h>

// Dims: B=16 S=512 D=768 H=12 DH=64 F=3072 LYR=12 NLAB=2; rows = B*S = 8192
typedef __bf16 bf16_t;
typedef __attribute__((ext_vector_type(8))) __bf16 bf16x8;
typedef __attribute__((ext_vector_type(4))) float f32x4;

typedef const __attribute__((address_space(1))) void av1_void;
typedef __attribute__((address_space(3))) void av3_void;

#define DEV static __device__ __forceinline__

DEV void gload16(const void* g, void* l) {
  __builtin_amdgcn_global_load_lds((av1_void*)g, (av3_void*)l, 16, 0, 0);
}

// ---- block reduction over 3 waves (block=192) ----
DEV float bsum3(float v, float* red) {
#pragma unroll
  for (int o = 32; o > 0; o >>= 1) v += __shfl_xor(v, o, 64);
  __syncthreads();
  if ((threadIdx.x & 63) == 0) red[threadIdx.x >> 6] = v;
  __syncthreads();
  return red[0] + red[1] + red[2];
}

// ---- embedding gather + LN -> x (fp32) ----
__global__ __launch_bounds__(192) void k_embed(
    const int* __restrict__ ids, const float* __restrict__ tok,
    const float* __restrict__ pos, const float* __restrict__ gam,
    const float* __restrict__ bet, float* __restrict__ x) {
  __shared__ float red[3];
  int row = blockIdx.x;          // b*512 + s
  int s = row & 511;
  int t = threadIdx.x;
  int id = ids[row];
  const float4 tv = *(const float4*)&tok[(size_t)id * 768 + t * 4];
  const float4 pv = *(const float4*)&pos[(size_t)s * 768 + t * 4];
  float v[4] = {tv.x + pv.x, tv.y + pv.y, tv.z + pv.z, tv.w + pv.w};
  float tot = bsum3(v[0] + v[1] + v[2] + v[3], red);
  float mu = tot * (1.f / 768.f);
  float sq = 0.f;
#pragma unroll
  for (int u = 0; u < 4; ++u) { float d = v[u] - mu; sq += d * d; }
  float var = bsum3(sq, red) * (1.f / 768.f);
  float rstd = rsqrtf(var + 1e-5f);
  const float4 g4 = *(const float4*)&gam[t * 4];
  const float4 b4 = *(const float4*)&bet[t * 4];
  float4 o;
  o.x = (v[0] - mu) * rstd * g4.x + b4.x;
  o.y = (v[1] - mu) * rstd * g4.y + b4.y;
  o.z = (v[2] - mu) * rstd * g4.z + b4.z;
  o.w = (v[3] - mu) * rstd * g4.w + b4.w;
  *(float4*)&x[(size_t)row * 768 + t * 4] = o;
}

// ---- LN: x (fp32) -> h (bf16) ----
__global__ __launch_bounds__(192) void k_ln(
    const float* __restrict__ xin, bf16_t* __restrict__ hout,
    const float* __restrict__ gam, const float* __restrict__ bet) {
  __shared__ float red[3];
  int row = blockIdx.x;
  int t = threadIdx.x;
  const float4 xv = *(const float4*)&xin[(size_t)row * 768 + t * 4];
  float v[4] = {xv.x, xv.y, xv.z, xv.w};
  float tot = bsum3(v[0] + v[1] + v[2] + v[3], red);
  float mu = tot * (1.f / 768.f);
  float sq = 0.f;
#pragma unroll
  for (int u = 0; u < 4; ++u) { float d = v[u] - mu; sq += d * d; }
  float var = bsum3(sq, red) * (1.f / 768.f);
  float rstd = rsqrtf(var + 1e-5f);
  const float4 g4 = *(const float4*)&gam[t * 4];
  const float4 b4 = *(const float4*)&bet[t * 4];
  union { bf16_t o[4]; uint2 u2; } pk;
  pk.o[0] = (bf16_t)((v[0] - mu) * rstd * g4.x + b4.x);
  pk.o[1] = (bf16_t)((v[1] - mu) * rstd * g4.y + b4.y);
  pk.o[2] = (bf16_t)((v[2] - mu) * rstd * g4.z + b4.z);
  pk.o[3] = (bf16_t)((v[3] - mu) * rstd * g4.w + b4.w);
  *(uint2*)&hout[(size_t)row * 768 + t * 4] = pk.u2;
}

// ---- transpose-convert fp32 [K][N] -> bf16 [N][K], per z-slice ----
__global__ __launch_bounds__(256) void k_convT(
    const float* __restrict__ in, size_t in_slice, bf16_t* __restrict__ out,
    size_t out_slice, int N, int K) {
  __shared__ float tbuf[32][33];
  int slice = blockIdx.z;
  const float* ip = in + (size_t)slice * in_slice;
  bf16_t* op = out + (size_t)slice * out_slice;
  int n0 = blockIdx.x * 32, k0 = blockIdx.y * 32;
  int c = threadIdx.x & 31, r8 = threadIdx.x >> 5;
#pragma unroll
  for (int i = 0; i < 4; ++i) {
    int rr = r8 + i * 8;
    tbuf[rr][c] = ip[(size_t)(k0 + rr) * N + n0 + c];
  }
  __syncthreads();
#pragma unroll
  for (int i = 0; i < 4; ++i) {
    int rr = r8 + i * 8;
    op[(size_t)(n0 + rr) * K + k0 + c] = (bf16_t)tbuf[c][rr];
  }
}

// ---- fused wq/wk/wv transpose-convert: 36 z-slices (3 mats x 12 heads) ----
__global__ __launch_bounds__(256) void k_convT3(
    const float* __restrict__ wq, const float* __restrict__ wk,
    const float* __restrict__ wv, bf16_t* __restrict__ out) {
  __shared__ float tbuf[32][33];
  int z = blockIdx.z;                 // 0..35
  int which = z / 12, slice = z % 12;
  const float* ip = (which == 0 ? wq : which == 1 ? wk : wv) +
                    (size_t)slice * 768 * 64;
  bf16_t* op = out + (size_t)which * 768 * 768 + (size_t)slice * 64 * 768;
  int n0 = blockIdx.x * 32, k0 = blockIdx.y * 32;   // N=64, K=768
  int c = threadIdx.x & 31, r8 = threadIdx.x >> 5;
#pragma unroll
  for (int i = 0; i < 4; ++i) {
    int rr = r8 + i * 8;
    tbuf[rr][c] = ip[(size_t)(k0 + rr) * 64 + n0 + c];
  }
  __syncthreads();
#pragma unroll
  for (int i = 0; i < 4; ++i) {
    int rr = r8 + i * 8;
    op[(size_t)(n0 + rr) * 768 + k0 + c] = (bf16_t)tbuf[c][rr];
  }
}

// ======================================================================
// 256x256 2-phase GEMM: C[M,N] = A[M,K] * Bt[N,K]^T  (bf16 in, fp32 acc)
// 8 waves (2Mx4N), BK=64, 128KB LDS double-buffer.
// Per K-tile: STAGE(next) -> COMPUTE(cur) -> __syncthreads().
// Both-sides XOR swizzle (linear LDS dest, inverse-swz source, swz read).
// EPI 0: store bf16; EPI 1: Cf += C + bias; EPI 2: gelu(C+bias) -> bf16
// Requires: M%256==0, N%256==0, K%64==0, grid %8==0.
// ======================================================================
template <int EPI>
__global__ __launch_bounds__(512, 2) void k_gemm2(
    const bf16_t* __restrict__ A, int lda, const bf16_t* __restrict__ Bt,
    int ldb, int K, float* __restrict__ Cf, bf16_t* __restrict__ Cb, int ldc,
    const float* __restrict__ bias, int gx) {
  __shared__ __attribute__((aligned(16))) bf16_t As[2][16384];
  __shared__ __attribute__((aligned(16))) bf16_t Bs[2][16384];
  const int nwg = gridDim.x;
  const int bid = blockIdx.x;
  const int cpx = nwg >> 3;                  // nwg % 8 == 0 guaranteed
  const int swz = (bid & 7) * cpx + (bid >> 3);
  const int bx = swz % gx, by = swz / gx;
  const int m0 = by << 8, n0 = bx << 8;
  const int tid = threadIdx.x;
  const int lane = tid & 63, w = tid >> 6;   // 8 waves
  const int wm = w >> 2, wn = w & 3;         // 2M x 4N
  const int r = lane & 15, g4 = lane >> 4;
  const int rx = r & 7;
  const int NT = K >> 6;

  f32x4 acc[8][4];
#pragma unroll
  for (int m = 0; m < 8; ++m)
#pragma unroll
    for (int n = 0; n < 4; ++n)
#pragma unroll
      for (int e = 0; e < 4; ++e) acc[m][n][e] = 0.f;

  // stage full 256x64 A-tile + B-tile of K-tile t into dbuf `buf`
  auto STAGE = [&](int buf, int t) {
    int k0 = t << 6;
#pragma unroll
    for (int u = 0; u < 4; ++u) {
      int s = u * 512 + tid;                 // slot in [256 rows][8 chunks]
      int row = s >> 3;
      int c = (s & 7) ^ (row & 7);           // inverse-swizzled source chunk
      gload16(A + (size_t)(m0 + row) * lda + k0 + c * 8,
              (char*)&As[buf][0] + (size_t)(u * 512 + (w << 6)) * 16);
    }
#pragma unroll
    for (int u = 0; u < 4; ++u) {
      int s = u * 512 + tid;
      int row = s >> 3;
      int c = (s & 7) ^ (row & 7);
      gload16(Bt + (size_t)(n0 + row) * ldb + k0 + c * 8,
              (char*)&Bs[buf][0] + (size_t)(u * 512 + (w << 6)) * 16);
    }
  };

  auto COMPUTE = [&](int buf) {
#pragma unroll
    for (int kk = 0; kk < 2; ++kk) {
      bf16x8 a8[8], b8[4];
      const int co = (((kk << 2) + g4) ^ rx) << 3;   // swizzled chunk offset
#pragma unroll
      for (int m = 0; m < 8; ++m) {
        int row = wm * 128 + m * 16 + r;             // row&7 == rx
        a8[m] = *(const bf16x8*)&As[buf][row * 64 + co];
      }
#pragma unroll
      for (int n = 0; n < 4; ++n) {
        int row = wn * 64 + n * 16 + r;              // row&7 == rx
        b8[n] = *(const bf16x8*)&Bs[buf][row * 64 + co];
      }
#pragma unroll
      for (int m = 0; m < 8; ++m)
#pragma unroll
        for (int n = 0; n < 4; ++n)
          acc[m][n] = __builtin_amdgcn_mfma_f32_16x16x32_bf16(a8[m], b8[n],
                                                              acc[m][n], 0, 0, 0);
    }
  };

  STAGE(0, 0);
  __syncthreads();               // drains vmcnt(0): buf0 ready
  int buf = 0;
  for (int t = 0; t < NT - 1; ++t) {
    STAGE(buf ^ 1, t + 1);       // in flight across the whole compute phase
    COMPUTE(buf);
    __syncthreads();             // next buf ready; old buf fully consumed
    buf ^= 1;
  }
  COMPUTE(buf);

  // epilogue (row-major store order)
  float bv[4];
  if constexpr (EPI != 0) {
#pragma unroll
    for (int n = 0; n < 4; ++n) bv[n] = bias[n0 + wn * 64 + n * 16 + r];
  }
#pragma unroll
  for (int m = 0; m < 8; ++m) {
#pragma unroll
    for (int j = 0; j < 4; ++j) {
      int row = m0 + wm * 128 + m * 16 + g4 * 4 + j;
#pragma unroll
      for (int n = 0; n < 4; ++n) {
        int col = n0 + wn * 64 + n * 16 + r;
        float v = acc[m][n][j];
        if constexpr (EPI == 0) {
          Cb[(size_t)row * ldc + col] = (bf16_t)v;
        } else if constexpr (EPI == 1) {
          size_t o = (size_t)row * ldc + col;
          Cf[o] += v + bv[n];
        } else {
          float tt = v + bv[n];
          float ge = 0.5f * tt * (1.f + erff(tt * 0.70710678118f));
          Cb[(size_t)row * ldc + col] = (bf16_t)ge;
        }
      }
    }
  }
}

// ---- lse[b,h,s] = logsumexp_t( q.k/8 ) ; 64 q-rows per block ----
__global__ __launch_bounds__(256) void k_lse(const bf16_t* __restrict__ qkv,
                                             float* __restrict__ lseb) {
  __shared__ __attribute__((aligned(16))) bf16_t Ks[512 * 64];
  __shared__ __attribute__((aligned(16))) bf16_t Qs[64 * 64];
  int bh = blockIdx.x;
  int b = bh / 12, hh = bh % 12;
  int s0 = blockIdx.y * 64;
  int tid = threadIdx.x, lane = tid & 63, w = tid >> 6;
  int r = lane & 15, g4 = lane >> 4;
  const bf16_t* kb = qkv + (size_t)b * 512 * 2304 + 768 + hh * 64;
  const bf16_t* qb = qkv + ((size_t)(b * 512 + s0)) * 2304 + hh * 64;
#pragma unroll
  for (int i = 0; i < 16; ++i) {
    int c = i * 256 + tid;
    gload16(kb + (size_t)(c >> 3) * 2304 + (c & 7) * 8,
            (char*)Ks + (size_t)(i * 256 + (w << 6)) * 16);
  }
#pragma unroll
  for (int i = 0; i < 2; ++i) {
    int c = i * 256 + tid;
    gload16(qb + (size_t)(c >> 3) * 2304 + (c & 7) * 8,
            (char*)Qs + (size_t)(i * 256 + (w << 6)) * 16);
  }
  __syncthreads();

  f32x4 acc[32];
#pragma unroll
  for (int n = 0; n < 32; ++n)
#pragma unroll
    for (int e = 0; e < 4; ++e) acc[n][e] = 0.f;

#pragma unroll
  for (int kk = 0; kk < 2; ++kk) {
    bf16x8 aq = *(const bf16x8*)&Qs[(w * 16 + r) * 64 + kk * 32 + g4 * 8];
#pragma unroll
    for (int n = 0; n < 32; ++n) {
      bf16x8 bk = *(const bf16x8*)&Ks[(n * 16 + r) * 64 + kk * 32 + g4 * 8];
      acc[n] = __builtin_amdgcn_mfma_f32_16x16x32_bf16(aq, bk, acc[n], 0, 0, 0);
    }
  }
#pragma unroll
  for (int j = 0; j < 4; ++j) {
    float mx = -1e30f;
#pragma unroll
    for (int n = 0; n < 32; ++n) mx = fmaxf(mx, acc[n][j] * 0.125f);
#pragma unroll
    for (int o = 1; o < 16; o <<= 1) mx = fmaxf(mx, __shfl_xor(mx, o, 64));
    float sm = 0.f;
#pragma unroll
    for (int n = 0; n < 32; ++n) sm += expf(acc[n][j] * 0.125f - mx);
#pragma unroll
    for (int o = 1; o < 16; o <<= 1) sm += __shfl_xor(sm, o, 64);
    if (r == 0)
      lseb[(size_t)bh * 512 + s0 + w * 16 + g4 * 4 + j] = mx + logf(sm);
  }
}

// ---- M[b,h] = K^T V / 8 (64x64) and sumv[b,h] = sum_t V ----
__global__ __launch_bounds__(256) void k_msumv(const bf16_t* __restrict__ qkv,
                                               float* __restrict__ Mb,
                                               float* __restrict__ sumv) {
  __shared__ __attribute__((aligned(16))) bf16_t Ks[128 * 64];
  __shared__ __attribute__((aligned(16))) float Vs[128 * 64];
  int bh = blockIdx.x;
  int b = bh / 12, hh = bh % 12;
  const bf16_t* kb = qkv + (size_t)b * 512 * 2304 + 768 + hh * 64;
  const bf16_t* vb = qkv + (size_t)b * 512 * 2304 + 1536 + hh * 64;
  int tid = threadIdx.x;
  int e1 = tid & 63, grp = tid >> 6;
  f32x4 macc[4];
#pragma unroll
  for (int jj = 0; jj < 4; ++jj)
#pragma unroll
    for (int e = 0; e < 4; ++e) macc[jj][e] = 0.f;
  float sv = 0.f;

  for (int t0 = 0; t0 < 512; t0 += 128) {
#pragma unroll
    for (int i = 0; i < 4; ++i) {
      int c = i * 256 + tid;
      gload16(kb + (size_t)(t0 + (c >> 3)) * 2304 + (c & 7) * 8,
              (char*)Ks + (size_t)(i * 256 + (grp << 6)) * 16);
    }
#pragma unroll
    for (int i = 0; i < 4; ++i) {
      int c = i * 256 + tid;
      int row = c >> 3, col = (c & 7) * 8;
      bf16x8 raw = *(const bf16x8*)(vb + (size_t)(t0 + row) * 2304 + col);
      f32x4 v0, v1;
#pragma unroll
      for (int u = 0; u < 4; ++u) { v0[u] = (float)raw[u]; v1[u] = (float)raw[u + 4]; }
      *(f32x4*)&Vs[row * 64 + col] = v0;
      *(f32x4*)&Vs[row * 64 + col + 4] = v1;
    }
    __syncthreads();
    for (int tt = 0; tt < 128; ++tt) {
      float kv = (float)Ks[tt * 64 + e1];
#pragma unroll
      for (int jj = 0; jj < 4; ++jj) {
        f32x4 vv = *(const f32x4*)&Vs[tt * 64 + grp * 16 + jj * 4];
        macc[jj] += kv * vv;
      }
    }
    if (tid < 64) {
      for (int tt = 0; tt < 128; ++tt) sv += Vs[tt * 64 + tid];
    }
    __syncthreads();
  }
#pragma unroll
  for (int jj = 0; jj < 4; ++jj)
#pragma unroll
    for (int u = 0; u < 4; ++u)
      Mb[(size_t)bh * 4096 + e1 * 64 + grp * 16 + jj * 4 + u] =
          macc[jj][u] * 0.125f;
  if (tid < 64) sumv[(size_t)bh * 64 + tid] = sv;
}

// ---- ctx[b,s,h*64+e2] = q[s,:].M[:,e2] - lse[s]*sumv[e2]  (bf16 out) ----
__global__ __launch_bounds__(256) void k_ctx(
    const bf16_t* __restrict__ qkv, const float* __restrict__ Mb,
    const float* __restrict__ sumv, const float* __restrict__ lseb,
    bf16_t* __restrict__ ctx) {
  __shared__ __attribute__((aligned(16))) bf16_t Qs[512 * 64];
  __shared__ __attribute__((aligned(16))) bf16_t Mt[64 * 64];
  int bh = blockIdx.x;
  int b = bh / 12, hh = bh % 12;
  int tid = threadIdx.x, lane = tid & 63, w = tid >> 6;
  int r = lane & 15, g4 = lane >> 4;
  const bf16_t* qb = qkv + (size_t)b * 512 * 2304 + hh * 64;
#pragma unroll
  for (int i = 0; i < 16; ++i) {
    int c = i * 256 + tid;
    gload16(qb + (size_t)(c >> 3) * 2304 + (c & 7) * 8,
            (char*)Qs + (size_t)(i * 256 + (w << 6)) * 16);
  }
  const float* Mp = Mb + (size_t)bh * 4096;
#pragma unroll
  for (int i = 0; i < 16; ++i) {
    int idx = i * 256 + tid;
    int ee1 = idx >> 6, ee2 = idx & 63;
    Mt[ee2 * 64 + ee1] = (bf16_t)Mp[idx];
  }
  __syncthreads();

  f32x4 acc[8][4];
#pragma unroll
  for (int m = 0; m < 8; ++m)
#pragma unroll
    for (int n = 0; n < 4; ++n)
#pragma unroll
      for (int e = 0; e < 4; ++e) acc[m][n][e] = 0.f;

#pragma unroll
  for (int kk = 0; kk < 2; ++kk) {
    bf16x8 bm[4];
#pragma unroll
    for (int n = 0; n < 4; ++n)
      bm[n] = *(const bf16x8*)&Mt[(n * 16 + r) * 64 + kk * 32 + g4 * 8];
#pragma unroll
    for (int m = 0; m < 8; ++m) {
      bf16x8 aq = *(const bf16x8*)&Qs[(w * 128 + m * 16 + r) * 64 + kk * 32 + g4 * 8];
#pragma unroll
      for (int n = 0; n < 4; ++n)
        acc[m][n] = __builtin_amdgcn_mfma_f32_16x16x32_bf16(aq, bm[n], acc[m][n], 0, 0, 0);
    }
  }
#pragma unroll
  for (int m = 0; m < 8; ++m) {
#pragma unroll
    for (int n = 0; n < 4; ++n) {
      int col = n * 16 + r;
      float svv = sumv[(size_t)bh * 64 + col];
#pragma unroll
      for (int j = 0; j < 4; ++j) {
        int s = w * 128 + m * 16 + g4 * 4 + j;
        float lv = lseb[(size_t)bh * 512 + s];
        float val = acc[m][n][j] - lv * svv;
        ctx[((size_t)(b * 512 + s)) * 768 + hh * 64 + col] = (bf16_t)val;
      }
    }
  }
}

// ---- final LN (row s=0 per batch) + classifier ----
__global__ __launch_bounds__(192) void k_final(
    const float* __restrict__ x, const float* __restrict__ gam,
    const float* __restrict__ bet, const float* __restrict__ cw,
    const float* __restrict__ cb, float* __restrict__ out) {
  __shared__ float red[3];
  int b = blockIdx.x, t = threadIdx.x;
  const float* xr = x + (size_t)b * 512 * 768;
  const float4 xv = *(const float4*)&xr[t * 4];
  float v[4] = {xv.x, xv.y, xv.z, xv.w};
  float tot = bsum3(v[0] + v[1] + v[2] + v[3], red);
  float mu = tot * (1.f / 768.f);
  float sq = 0.f;
#pragma unroll
  for (int u = 0; u < 4; ++u) { float d = v[u] - mu; sq += d * d; }
  float var = bsum3(sq, red) * (1.f / 768.f);
  float rstd = rsqrtf(var + 1e-5f);
  const float4 g4 = *(const float4*)&gam[t * 4];
  const float4 b4 = *(const float4*)&bet[t * 4];
  float nv[4];
  nv[0] = (v[0] - mu) * rstd * g4.x + b4.x;
  nv[1] = (v[1] - mu) * rstd * g4.y + b4.y;
  nv[2] = (v[2] - mu) * rstd * g4.z + b4.z;
  nv[3] = (v[3] - mu) * rstd * g4.w + b4.w;
  const float4 wa = *(const float4*)&cw[t * 8];
  const float4 wb = *(const float4*)&cw[t * 8 + 4];
  float d0 = nv[0] * wa.x + nv[1] * wa.z + nv[2] * wb.x + nv[3] * wb.z;
  float d1 = nv[0] * wa.y + nv[1] * wa.w + nv[2] * wb.y + nv[3] * wb.w;
  d0 = bsum3(d0, red);
  d1 = bsum3(d1, red);
  if (t == 0) {
    out[b * 2 + 0] = d0 + cb[0];
    out[b * 2 + 1] = d1 + cb[1];
  }
}

// ---- workspace layout ----
static constexpr size_t OFF_X = 0;                                  // f32 8192x768
static constexpr size_t OFF_H = OFF_X + 8192ull * 768 * 4;          // bf16 8192x768
static constexpr size_t OFF_QG = OFF_H + 8192ull * 768 * 2;         // bf16 arena (qkv 8192x2304 | gelu 8192x3072)
static constexpr size_t OFF_CTX = OFF_QG + 8192ull * 3072 * 2;      // bf16 8192x768
static constexpr size_t OFF_W = OFF_CTX + 8192ull * 768 * 2;        // bf16 7077888
static constexpr size_t OFF_LSE = OFF_W + 7077888ull * 2;           // f32 192*512
static constexpr size_t OFF_SV = OFF_LSE + 192ull * 512 * 4;        // f32 192*64
static constexpr size_t OFF_M = OFF_SV + 192ull * 64 * 4;           // f32 192*64*64
static constexpr size_t WS_NEED = OFF_M + 192ull * 64 * 64 * 4;

extern "C" void kernel_launch(void* const* d_in, const int* in_sizes, int n_in,
                              void* d_out, int out_size, void* d_ws,
                              size_t ws_size, hipStream_t stream) {
  const int* ids = (const int*)d_in[0];
  const float* tok = (const float*)d_in[1];
  const float* pos = (const float*)d_in[2];
  const float* eln_s = (const float*)d_in[3];
  const float* eln_b = (const float*)d_in[4];
  const float* wq = (const float*)d_in[5];
  const float* wk = (const float*)d_in[6];
  const float* wv = (const float*)d_in[7];
  const float* wo = (const float*)d_in[8];
  const float* wo_b = (const float*)d_in[9];
  const float* ln1_s = (const float*)d_in[10];
  const float* ln1_b = (const float*)d_in[11];
  const float* ln2_s = (const float*)d_in[12];
  const float* ln2_b = (const float*)d_in[13];
  const float* ff1w = (const float*)d_in[14];
  const float* ff1b = (const float*)d_in[15];
  const float* ff2w = (const float*)d_in[16];
  const float* ff2b = (const float*)d_in[17];
  const float* fln_s = (const float*)d_in[18];
  const float* fln_b = (const float*)d_in[19];
  const float* cw = (const float*)d_in[20];
  const float* cb = (const float*)d_in[21];
  float* out = (float*)d_out;

  if (ws_size < WS_NEED) return;  // workspace too small; will fail validation loudly

  char* ws = (char*)d_ws;
  float* x = (float*)(ws + OFF_X);
  bf16_t* h = (bf16_t*)(ws + OFF_H);
  bf16_t* qkv = (bf16_t*)(ws + OFF_QG);
  bf16_t* gbuf = (bf16_t*)(ws + OFF_QG);
  bf16_t* ctx = (bf16_t*)(ws + OFF_CTX);
  bf16_t* wT = (bf16_t*)(ws + OFF_W);
  float* lseb = (float*)(ws + OFF_LSE);
  float* sv = (float*)(ws + OFF_SV);
  float* Mb = (float*)(ws + OFF_M);

  bf16_t* qkvT = wT;                  // [2304][768]
  bf16_t* woT = wT + 1769472;         // [768][768]
  bf16_t* ff1T = wT + 2359296;        // [3072][768]
  bf16_t* ff2T = wT + 4718592;        // [768][3072]

  k_embed<<<8192, 192, 0, stream>>>(ids, tok, pos, eln_s, eln_b, x);

  for (int l = 0; l < 12; ++l) {
    k_ln<<<8192, 192, 0, stream>>>(x, h, ln1_s + l * 768, ln1_b + l * 768);
    // weight convert+transpose (per layer, reused buffers)
    k_convT3<<<dim3(2, 24, 36), 256, 0, stream>>>(wq + (size_t)l * 12 * 768 * 64,
                                                  wk + (size_t)l * 12 * 768 * 64,
                                                  wv + (size_t)l * 12 * 768 * 64,
                                                  qkvT);
    k_convT<<<dim3(24, 24, 1), 256, 0, stream>>>(wo + (size_t)l * 768 * 768, 0,
                                                 woT, 0, 768, 768);
    k_convT<<<dim3(96, 24, 1), 256, 0, stream>>>(ff1w + (size_t)l * 768 * 3072, 0,
                                                 ff1T, 0, 3072, 768);
    k_convT<<<dim3(24, 96, 1), 256, 0, stream>>>(ff2w + (size_t)l * 3072 * 768, 0,
                                                 ff2T, 0, 768, 3072);
    // QKV projection: M=8192 N=2304 K=768 -> grid 32*9=288
    k_gemm2<0><<<288, 512, 0, stream>>>(h, 768, qkvT, 768, 768, nullptr,
                                        qkv, 2304, nullptr, 9);
    // attention (log-softmax decomposition)
    k_lse<<<dim3(192, 8), 256, 0, stream>>>(qkv, lseb);
    k_msumv<<<192, 256, 0, stream>>>(qkv, Mb, sv);
    k_ctx<<<192, 256, 0, stream>>>(qkv, Mb, sv, lseb, ctx);
    // output projection + residual: M=8192 N=768 K=768 -> grid 32*3=96
    k_gemm2<1><<<96, 512, 0, stream>>>(ctx, 768, woT, 768, 768, x,
                                       nullptr, 768, wo_b + l * 768, 3);
    // FFN
    k_ln<<<8192, 192, 0, stream>>>(x, h, ln2_s + l * 768, ln2_b + l * 768);
    // FF1: M=8192 N=3072 K=768 -> grid 32*12=384
    k_gemm2<2><<<384, 512, 0, stream>>>(h, 768, ff1T, 768, 768, nullptr,
                                        gbuf, 3072, ff1b + l * 3072, 12);
    // FF2: M=8192 N=768 K=3072 -> grid 32*3=96
    k_gemm2<1><<<96, 512, 0, stream>>>(gbuf, 3072, ff2T, 3072, 3072, x,
                                       nullptr, 768, ff2b + l * 768, 3);
  }
  k_final<<<16, 192, 0, stream>>>(x, fln_s, fln_b, cw, cb, out);
}

// Round 8
// 4645.079 us; speedup vs baseline: 1.2226x; 1.2226x over previous
//
#include <hip/hip_runtime.h>
#include <hip/hip_bf16.h>
#include <math.h>

// Dims: B=16 S=512 D=768 H=12 DH=64 F=3072 LYR=12 NLAB=2; rows = B*S = 8192
typedef __bf16 bf16_t;
typedef __attribute__((ext_vector_type(8))) __bf16 bf16x8;
typedef __attribute__((ext_vector_type(4))) float f32x4;

typedef const __attribute__((address_space(1))) void av1_void;
typedef __attribute__((address_space(3))) void av3_void;

#define DEV static __device__ __forceinline__

DEV void gload16(const void* g, void* l) {
  __builtin_amdgcn_global_load_lds((av1_void*)g, (av3_void*)l, 16, 0, 0);
}

// ---- block reduction over 3 waves (block=192) ----
DEV float bsum3(float v, float* red) {
#pragma unroll
  for (int o = 32; o > 0; o >>= 1) v += __shfl_xor(v, o, 64);
  __syncthreads();
  if ((threadIdx.x & 63) == 0) red[threadIdx.x >> 6] = v;
  __syncthreads();
  return red[0] + red[1] + red[2];
}

// ---- embedding gather + emb-LN -> x (fp32), then ln1(layer0) -> h (bf16) ----
__global__ __launch_bounds__(192) void k_embed(
    const int* __restrict__ ids, const float* __restrict__ tok,
    const float* __restrict__ pos, const float* __restrict__ gam,
    const float* __restrict__ bet, const float* __restrict__ gam2,
    const float* __restrict__ bet2, float* __restrict__ x,
    bf16_t* __restrict__ h) {
  __shared__ float red[3];
  int row = blockIdx.x;          // b*512 + s
  int s = row & 511;
  int t = threadIdx.x;
  int id = ids[row];
  const float4 tv = *(const float4*)&tok[(size_t)id * 768 + t * 4];
  const float4 pv = *(const float4*)&pos[(size_t)s * 768 + t * 4];
  float v[4] = {tv.x + pv.x, tv.y + pv.y, tv.z + pv.z, tv.w + pv.w};
  float tot = bsum3(v[0] + v[1] + v[2] + v[3], red);
  float mu = tot * (1.f / 768.f);
  float sq = 0.f;
#pragma unroll
  for (int u = 0; u < 4; ++u) { float d = v[u] - mu; sq += d * d; }
  float var = bsum3(sq, red) * (1.f / 768.f);
  float rstd = rsqrtf(var + 1e-5f);
  const float4 g4 = *(const float4*)&gam[t * 4];
  const float4 b4 = *(const float4*)&bet[t * 4];
  float o[4];
  o[0] = (v[0] - mu) * rstd * g4.x + b4.x;
  o[1] = (v[1] - mu) * rstd * g4.y + b4.y;
  o[2] = (v[2] - mu) * rstd * g4.z + b4.z;
  o[3] = (v[3] - mu) * rstd * g4.w + b4.w;
  float4 ov = {o[0], o[1], o[2], o[3]};
  *(float4*)&x[(size_t)row * 768 + t * 4] = ov;
  // second LN (ln1 of layer 0) -> h
  float tot2 = bsum3(o[0] + o[1] + o[2] + o[3], red);
  float mu2 = tot2 * (1.f / 768.f);
  float sq2 = 0.f;
#pragma unroll
  for (int u = 0; u < 4; ++u) { float d = o[u] - mu2; sq2 += d * d; }
  float var2 = bsum3(sq2, red) * (1.f / 768.f);
  float rstd2 = rsqrtf(var2 + 1e-5f);
  const float4 G = *(const float4*)&gam2[t * 4];
  const float4 Bb = *(const float4*)&bet2[t * 4];
  union { bf16_t ob[4]; uint2 u2; } pk;
  pk.ob[0] = (bf16_t)((o[0] - mu2) * rstd2 * G.x + Bb.x);
  pk.ob[1] = (bf16_t)((o[1] - mu2) * rstd2 * G.y + Bb.y);
  pk.ob[2] = (bf16_t)((o[2] - mu2) * rstd2 * G.z + Bb.z);
  pk.ob[3] = (bf16_t)((o[3] - mu2) * rstd2 * G.w + Bb.w);
  *(uint2*)&h[(size_t)row * 768 + t * 4] = pk.u2;
}

// ---- LN: x (fp32) -> h (bf16) ----
__global__ __launch_bounds__(192) void k_ln(
    const float* __restrict__ xin, bf16_t* __restrict__ hout,
    const float* __restrict__ gam, const float* __restrict__ bet) {
  __shared__ float red[3];
  int row = blockIdx.x;
  int t = threadIdx.x;
  const float4 xv = *(const float4*)&xin[(size_t)row * 768 + t * 4];
  float v[4] = {xv.x, xv.y, xv.z, xv.w};
  float tot = bsum3(v[0] + v[1] + v[2] + v[3], red);
  float mu = tot * (1.f / 768.f);
  float sq = 0.f;
#pragma unroll
  for (int u = 0; u < 4; ++u) { float d = v[u] - mu; sq += d * d; }
  float var = bsum3(sq, red) * (1.f / 768.f);
  float rstd = rsqrtf(var + 1e-5f);
  const float4 g4 = *(const float4*)&gam[t * 4];
  const float4 b4 = *(const float4*)&bet[t * 4];
  union { bf16_t o[4]; uint2 u2; } pk;
  pk.o[0] = (bf16_t)((v[0] - mu) * rstd * g4.x + b4.x);
  pk.o[1] = (bf16_t)((v[1] - mu) * rstd * g4.y + b4.y);
  pk.o[2] = (bf16_t)((v[2] - mu) * rstd * g4.z + b4.z);
  pk.o[3] = (bf16_t)((v[3] - mu) * rstd * g4.w + b4.w);
  *(uint2*)&hout[(size_t)row * 768 + t * 4] = pk.u2;
}

// ---- transpose-convert fp32 [K][N] -> bf16 [N][K], per z-slice ----
__global__ __launch_bounds__(256) void k_convT(
    const float* __restrict__ in, size_t in_slice, bf16_t* __restrict__ out,
    size_t out_slice, int N, int K) {
  __shared__ float tbuf[32][33];
  int slice = blockIdx.z;
  const float* ip = in + (size_t)slice * in_slice;
  bf16_t* op = out + (size_t)slice * out_slice;
  int n0 = blockIdx.x * 32, k0 = blockIdx.y * 32;
  int c = threadIdx.x & 31, r8 = threadIdx.x >> 5;
#pragma unroll
  for (int i = 0; i < 4; ++i) {
    int rr = r8 + i * 8;
    tbuf[rr][c] = ip[(size_t)(k0 + rr) * N + n0 + c];
  }
  __syncthreads();
#pragma unroll
  for (int i = 0; i < 4; ++i) {
    int rr = r8 + i * 8;
    op[(size_t)(n0 + rr) * K + k0 + c] = (bf16_t)tbuf[c][rr];
  }
}

// ---- fused wq/wk/wv transpose-convert, NL layers: z = l*36 + which*12 + head
__global__ __launch_bounds__(256) void k_convT3(
    const float* __restrict__ wq, const float* __restrict__ wk,
    const float* __restrict__ wv, bf16_t* __restrict__ out,
    size_t in_lstride, size_t out_lstride) {
  __shared__ float tbuf[32][33];
  int z = blockIdx.z;
  int l = z / 36, r = z % 36;
  int which = r / 12, head = r % 12;
  const float* ip = (which == 0 ? wq : which == 1 ? wk : wv) +
                    (size_t)l * in_lstride + (size_t)head * 768 * 64;
  bf16_t* op = out + (size_t)l * out_lstride + (size_t)which * 768 * 768 +
               (size_t)head * 64 * 768;
  int n0 = blockIdx.x * 32, k0 = blockIdx.y * 32;   // N=64, K=768
  int c = threadIdx.x & 31, r8 = threadIdx.x >> 5;
#pragma unroll
  for (int i = 0; i < 4; ++i) {
    int rr = r8 + i * 8;
    tbuf[rr][c] = ip[(size_t)(k0 + rr) * 64 + n0 + c];
  }
  __syncthreads();
#pragma unroll
  for (int i = 0; i < 4; ++i) {
    int rr = r8 + i * 8;
    op[(size_t)(n0 + rr) * 768 + k0 + c] = (bf16_t)tbuf[c][rr];
  }
}

// ======================================================================
// 128x128 2-phase GEMM (round-2 proven config): BK=64, double-buffered
// LDS (64KB), 4 waves, both-sides XOR swizzle, 1 barrier per K-step.
// EPI 0: store bf16; EPI 1: Cf += C + bias; EPI 2: gelu(C+bias) -> bf16
// ======================================================================
template <int EPI>
__global__ __launch_bounds__(256) void k_gemm(
    const bf16_t* __restrict__ A, int lda, const bf16_t* __restrict__ Bt,
    int ldb, int K, float* __restrict__ Cf, bf16_t* __restrict__ Cb, int ldc,
    const float* __restrict__ bias) {
  __shared__ __attribute__((aligned(16))) bf16_t As[2][128 * 64];
  __shared__ __attribute__((aligned(16))) bf16_t Bs[2][128 * 64];
  const int tid = threadIdx.x;
  const int m0 = blockIdx.y * 128, n0 = blockIdx.x * 128;
  const int lane = tid & 63, w = tid >> 6;
  const int wm = w >> 1, wn = w & 1;
  const int r = lane & 15, g4 = lane >> 4;

  f32x4 acc[4][4];
#pragma unroll
  for (int m = 0; m < 4; ++m)
#pragma unroll
    for (int n = 0; n < 4; ++n)
#pragma unroll
      for (int e = 0; e < 4; ++e) acc[m][n][e] = 0.f;

  auto STAGE = [&](int buf, int k0) {
#pragma unroll
    for (int i = 0; i < 4; ++i) {
      int s = i * 256 + tid;           // 16B slot index in [128][8]
      int row = s >> 3;
      int c = (s & 7) ^ (row & 7);     // inverse-swizzled source chunk
      gload16(A + (size_t)(m0 + row) * lda + k0 + c * 8,
              (char*)&As[buf][0] + (size_t)(i * 256 + (w << 6)) * 16);
    }
#pragma unroll
    for (int i = 0; i < 4; ++i) {
      int s = i * 256 + tid;
      int row = s >> 3;
      int c = (s & 7) ^ (row & 7);
      gload16(Bt + (size_t)(n0 + row) * ldb + k0 + c * 8,
              (char*)&Bs[buf][0] + (size_t)(i * 256 + (w << 6)) * 16);
    }
  };

  auto COMPUTE = [&](int buf) {
#pragma unroll
    for (int kk = 0; kk < 2; ++kk) {
      bf16x8 af[4], bb[4];
#pragma unroll
      for (int m = 0; m < 4; ++m) {
        int row = wm * 64 + m * 16 + r;
        af[m] = *(const bf16x8*)&As[buf][row * 64 +
                                        (((kk << 2) + g4) ^ (row & 7)) * 8];
      }
#pragma unroll
      for (int n = 0; n < 4; ++n) {
        int row = wn * 64 + n * 16 + r;
        bb[n] = *(const bf16x8*)&Bs[buf][row * 64 +
                                         (((kk << 2) + g4) ^ (row & 7)) * 8];
      }
#pragma unroll
      for (int m = 0; m < 4; ++m)
#pragma unroll
        for (int n = 0; n < 4; ++n)
          acc[m][n] = __builtin_amdgcn_mfma_f32_16x16x32_bf16(af[m], bb[n],
                                                              acc[m][n], 0, 0, 0);
    }
  };

  const int nt = K >> 6;
  STAGE(0, 0);
  __syncthreads();
  int cur = 0;
  for (int t = 0; t < nt - 1; ++t) {
    STAGE(cur ^ 1, (t + 1) << 6);
    COMPUTE(cur);
    __syncthreads();
    cur ^= 1;
  }
  COMPUTE(cur);

#pragma unroll
  for (int m = 0; m < 4; ++m) {
#pragma unroll
    for (int n = 0; n < 4; ++n) {
      int col = n0 + wn * 64 + n * 16 + r;
      float bv = 0.f;
      if constexpr (EPI != 0) bv = bias[col];
#pragma unroll
      for (int j = 0; j < 4; ++j) {
        int row = m0 + wm * 64 + m * 16 + g4 * 4 + j;
        float v = acc[m][n][j];
        if constexpr (EPI == 0) {
          Cb[(size_t)row * ldc + col] = (bf16_t)v;
        } else if constexpr (EPI == 1) {
          size_t o = (size_t)row * ldc + col;
          Cf[o] += v + bv;
        } else {
          float tt = v + bv;
          float ge = 0.5f * tt * (1.f + erff(tt * 0.70710678118f));
          Cb[(size_t)row * ldc + col] = (bf16_t)ge;
        }
      }
    }
  }
}

// ---- lse[b,h,s] = logsumexp_t( q.k/8 ) ; 64 q-rows per block ----
__global__ __launch_bounds__(256) void k_lse(const bf16_t* __restrict__ qkv,
                                             float* __restrict__ lseb) {
  __shared__ __attribute__((aligned(16))) bf16_t Ks[512 * 64];
  __shared__ __attribute__((aligned(16))) bf16_t Qs[64 * 64];
  int bh = blockIdx.x;
  int b = bh / 12, hh = bh % 12;
  int s0 = blockIdx.y * 64;
  int tid = threadIdx.x, lane = tid & 63, w = tid >> 6;
  int r = lane & 15, g4 = lane >> 4;
  const bf16_t* kb = qkv + (size_t)b * 512 * 2304 + 768 + hh * 64;
  const bf16_t* qb = qkv + ((size_t)(b * 512 + s0)) * 2304 + hh * 64;
#pragma unroll
  for (int i = 0; i < 16; ++i) {
    int c = i * 256 + tid;
    gload16(kb + (size_t)(c >> 3) * 2304 + (c & 7) * 8,
            (char*)Ks + (size_t)(i * 256 + (w << 6)) * 16);
  }
#pragma unroll
  for (int i = 0; i < 2; ++i) {
    int c = i * 256 + tid;
    gload16(qb + (size_t)(c >> 3) * 2304 + (c & 7) * 8,
            (char*)Qs + (size_t)(i * 256 + (w << 6)) * 16);
  }
  __syncthreads();

  f32x4 acc[32];
#pragma unroll
  for (int n = 0; n < 32; ++n)
#pragma unroll
    for (int e = 0; e < 4; ++e) acc[n][e] = 0.f;

#pragma unroll
  for (int kk = 0; kk < 2; ++kk) {
    bf16x8 aq = *(const bf16x8*)&Qs[(w * 16 + r) * 64 + kk * 32 + g4 * 8];
#pragma unroll
    for (int n = 0; n < 32; ++n) {
      bf16x8 bk = *(const bf16x8*)&Ks[(n * 16 + r) * 64 + kk * 32 + g4 * 8];
      acc[n] = __builtin_amdgcn_mfma_f32_16x16x32_bf16(aq, bk, acc[n], 0, 0, 0);
    }
  }
#pragma unroll
  for (int j = 0; j < 4; ++j) {
    float mx = -1e30f;
#pragma unroll
    for (int n = 0; n < 32; ++n) mx = fmaxf(mx, acc[n][j] * 0.125f);
#pragma unroll
    for (int o = 1; o < 16; o <<= 1) mx = fmaxf(mx, __shfl_xor(mx, o, 64));
    float sm = 0.f;
#pragma unroll
    for (int n = 0; n < 32; ++n) sm += expf(acc[n][j] * 0.125f - mx);
#pragma unroll
    for (int o = 1; o < 16; o <<= 1) sm += __shfl_xor(sm, o, 64);
    if (r == 0)
      lseb[(size_t)bh * 512 + s0 + w * 16 + g4 * 4 + j] = mx + logf(sm);
  }
}

// ---- fused attn tail: M=K^TV/8 & sumv in LDS, then ctx = qM - lse*sumv ----
__global__ __launch_bounds__(256) void k_attn2(
    const bf16_t* __restrict__ qkv, const float* __restrict__ lseb,
    bf16_t* __restrict__ ctx) {
  __shared__ __attribute__((aligned(16))) char arena[65536];  // Ks+Vs | Qs
  __shared__ __attribute__((aligned(16))) bf16_t Mt[64 * 64];
  __shared__ float svs[64];
  bf16_t* Ks = (bf16_t*)arena;                 // [128][64] bf16 (16KB)
  float* Vs = (float*)(arena + 16384);         // [128][64] f32 (32KB)
  bf16_t* Qs = (bf16_t*)arena;                 // [512][64] bf16 (64KB), phase 2

  int bh = blockIdx.x;
  int b = bh / 12, hh = bh % 12;
  int tid = threadIdx.x, lane = tid & 63, w = tid >> 6;
  const bf16_t* kb = qkv + (size_t)b * 512 * 2304 + 768 + hh * 64;
  const bf16_t* vb = qkv + (size_t)b * 512 * 2304 + 1536 + hh * 64;
  const bf16_t* qb = qkv + (size_t)b * 512 * 2304 + hh * 64;

  // ---- phase 1: M = K^T V / 8 (64x64), sumv ----
  int e1 = lane, grp = w;                      // e1 over K-dim, grp over e2/16
  f32x4 macc[4];
#pragma unroll
  for (int jj = 0; jj < 4; ++jj)
#pragma unroll
    for (int e = 0; e < 4; ++e) macc[jj][e] = 0.f;
  float sv = 0.f;

  for (int t0 = 0; t0 < 512; t0 += 128) {
#pragma unroll
    for (int i = 0; i < 4; ++i) {
      int c = i * 256 + tid;
      gload16(kb + (size_t)(t0 + (c >> 3)) * 2304 + (c & 7) * 8,
              (char*)Ks + (size_t)(i * 256 + (w << 6)) * 16);
    }
#pragma unroll
    for (int i = 0; i < 4; ++i) {
      int c = i * 256 + tid;
      int row = c >> 3, col = (c & 7) * 8;
      bf16x8 raw = *(const bf16x8*)(vb + (size_t)(t0 + row) * 2304 + col);
      f32x4 v0, v1;
#pragma unroll
      for (int u = 0; u < 4; ++u) { v0[u] = (float)raw[u]; v1[u] = (float)raw[u + 4]; }
      *(f32x4*)&Vs[row * 64 + col] = v0;
      *(f32x4*)&Vs[row * 64 + col + 4] = v1;
    }
    __syncthreads();
    for (int tt = 0; tt < 128; ++tt) {
      float kv = (float)Ks[tt * 64 + e1];
#pragma unroll
      for (int jj = 0; jj < 4; ++jj) {
        f32x4 vv = *(const f32x4*)&Vs[tt * 64 + grp * 16 + jj * 4];
        macc[jj] += kv * vv;
      }
    }
    if (tid < 64) {
      for (int tt = 0; tt < 128; ++tt) sv += Vs[tt * 64 + tid];
    }
    __syncthreads();
  }
  // write M^T into LDS as bf16: Mt[e2][e1]
#pragma unroll
  for (int jj = 0; jj < 4; ++jj)
#pragma unroll
    for (int u = 0; u < 4; ++u)
      Mt[(grp * 16 + jj * 4 + u) * 64 + e1] = (bf16_t)(macc[jj][u] * 0.125f);
  if (tid < 64) svs[tid] = sv;
  __syncthreads();                              // arena free, Mt/svs ready

  // ---- phase 2: ctx = q.M - lse*sumv ----
  int r = lane & 15, g4 = lane >> 4;
#pragma unroll
  for (int i = 0; i < 16; ++i) {
    int c = i * 256 + tid;
    gload16(qb + (size_t)(c >> 3) * 2304 + (c & 7) * 8,
            (char*)Qs + (size_t)(i * 256 + (w << 6)) * 16);
  }
  __syncthreads();                              // Qs ready

  f32x4 acc[8][4];
#pragma unroll
  for (int m = 0; m < 8; ++m)
#pragma unroll
    for (int n = 0; n < 4; ++n)
#pragma unroll
      for (int e = 0; e < 4; ++e) acc[m][n][e] = 0.f;

#pragma unroll
  for (int kk = 0; kk < 2; ++kk) {
    bf16x8 bm[4];
#pragma unroll
    for (int n = 0; n < 4; ++n)
      bm[n] = *(const bf16x8*)&Mt[(n * 16 + r) * 64 + kk * 32 + g4 * 8];
#pragma unroll
    for (int m = 0; m < 8; ++m) {
      bf16x8 aq = *(const bf16x8*)&Qs[(w * 128 + m * 16 + r) * 64 + kk * 32 + g4 * 8];
#pragma unroll
      for (int n = 0; n < 4; ++n)
        acc[m][n] = __builtin_amdgcn_mfma_f32_16x16x32_bf16(aq, bm[n], acc[m][n], 0, 0, 0);
    }
  }
#pragma unroll
  for (int m = 0; m < 8; ++m) {
#pragma unroll
    for (int n = 0; n < 4; ++n) {
      int col = n * 16 + r;
      float svv = svs[col];
#pragma unroll
      for (int j = 0; j < 4; ++j) {
        int s = w * 128 + m * 16 + g4 * 4 + j;
        float lv = lseb[(size_t)bh * 512 + s];
        float val = acc[m][n][j] - lv * svv;
        ctx[((size_t)(b * 512 + s)) * 768 + hh * 64 + col] = (bf16_t)val;
      }
    }
  }
}

// ---- final LN (row s=0 per batch) + classifier ----
__global__ __launch_bounds__(192) void k_final(
    const float* __restrict__ x, const float* __restrict__ gam,
    const float* __restrict__ bet, const float* __restrict__ cw,
    const float* __restrict__ cb, float* __restrict__ out) {
  __shared__ float red[3];
  int b = blockIdx.x, t = threadIdx.x;
  const float* xr = x + (size_t)b * 512 * 768;
  const float4 xv = *(const float4*)&xr[t * 4];
  float v[4] = {xv.x, xv.y, xv.z, xv.w};
  float tot = bsum3(v[0] + v[1] + v[2] + v[3], red);
  float mu = tot * (1.f / 768.f);
  float sq = 0.f;
#pragma unroll
  for (int u = 0; u < 4; ++u) { float d = v[u] - mu; sq += d * d; }
  float var = bsum3(sq, red) * (1.f / 768.f);
  float rstd = rsqrtf(var + 1e-5f);
  const float4 g4 = *(const float4*)&gam[t * 4];
  const float4 b4 = *(const float4*)&bet[t * 4];
  float nv[4];
  nv[0] = (v[0] - mu) * rstd * g4.x + b4.x;
  nv[1] = (v[1] - mu) * rstd * g4.y + b4.y;
  nv[2] = (v[2] - mu) * rstd * g4.z + b4.z;
  nv[3] = (v[3] - mu) * rstd * g4.w + b4.w;
  const float4 wa = *(const float4*)&cw[t * 8];
  const float4 wb = *(const float4*)&cw[t * 8 + 4];
  float d0 = nv[0] * wa.x + nv[1] * wa.z + nv[2] * wb.x + nv[3] * wb.z;
  float d1 = nv[0] * wa.y + nv[1] * wa.w + nv[2] * wb.y + nv[3] * wb.w;
  d0 = bsum3(d0, red);
  d1 = bsum3(d1, red);
  if (t == 0) {
    out[b * 2 + 0] = d0 + cb[0];
    out[b * 2 + 1] = d1 + cb[1];
  }
}

// ---- workspace layout ----
static constexpr size_t OFF_X = 0;                                  // f32 8192x768
static constexpr size_t OFF_H = OFF_X + 8192ull * 768 * 4;          // bf16 8192x768
static constexpr size_t OFF_QG = OFF_H + 8192ull * 768 * 2;         // bf16 arena (qkv | gelu)
static constexpr size_t OFF_CTX = OFF_QG + 8192ull * 3072 * 2;      // bf16 8192x768
static constexpr size_t OFF_LSE = OFF_CTX + 8192ull * 768 * 2;      // f32 192*512
static constexpr size_t OFF_W = OFF_LSE + 192ull * 512 * 4;         // bf16 weights
static constexpr size_t WPL = 7077888;                              // elems per layer
static constexpr size_t WS_SMALL = OFF_W + WPL * 2;                 // 1-layer buffer
static constexpr size_t WS_BIG = OFF_W + 12ull * WPL * 2;           // all layers

extern "C" void kernel_launch(void* const* d_in, const int* in_sizes, int n_in,
                              void* d_out, int out_size, void* d_ws,
                              size_t ws_size, hipStream_t stream) {
  const int* ids = (const int*)d_in[0];
  const float* tok = (const float*)d_in[1];
  const float* pos = (const float*)d_in[2];
  const float* eln_s = (const float*)d_in[3];
  const float* eln_b = (const float*)d_in[4];
  const float* wq = (const float*)d_in[5];
  const float* wk = (const float*)d_in[6];
  const float* wv = (const float*)d_in[7];
  const float* wo = (const float*)d_in[8];
  const float* wo_b = (const float*)d_in[9];
  const float* ln1_s = (const float*)d_in[10];
  const float* ln1_b = (const float*)d_in[11];
  const float* ln2_s = (const float*)d_in[12];
  const float* ln2_b = (const float*)d_in[13];
  const float* ff1w = (const float*)d_in[14];
  const float* ff1b = (const float*)d_in[15];
  const float* ff2w = (const float*)d_in[16];
  const float* ff2b = (const float*)d_in[17];
  const float* fln_s = (const float*)d_in[18];
  const float* fln_b = (const float*)d_in[19];
  const float* cw = (const float*)d_in[20];
  const float* cb = (const float*)d_in[21];
  float* out = (float*)d_out;

  if (ws_size < WS_SMALL) return;
  const bool big = ws_size >= WS_BIG;

  char* ws = (char*)d_ws;
  float* x = (float*)(ws + OFF_X);
  bf16_t* h = (bf16_t*)(ws + OFF_H);
  bf16_t* qkv = (bf16_t*)(ws + OFF_QG);
  bf16_t* gbuf = (bf16_t*)(ws + OFF_QG);
  bf16_t* ctx = (bf16_t*)(ws + OFF_CTX);
  float* lseb = (float*)(ws + OFF_LSE);
  bf16_t* wT = (bf16_t*)(ws + OFF_W);

  // embedding + emb-LN + ln1(layer0)
  k_embed<<<8192, 192, 0, stream>>>(ids, tok, pos, eln_s, eln_b,
                                    ln1_s, ln1_b, x, h);

  if (big) {
    // convert ALL layers' weights upfront: 4 launches
    k_convT3<<<dim3(2, 24, 432), 256, 0, stream>>>(wq, wk, wv, wT,
                                                   589824, WPL);
    k_convT<<<dim3(24, 24, 12), 256, 0, stream>>>(wo, 589824,
                                                  wT + 1769472, WPL, 768, 768);
    k_convT<<<dim3(96, 24, 12), 256, 0, stream>>>(ff1w, 2359296,
                                                  wT + 2359296, WPL, 3072, 768);
    k_convT<<<dim3(24, 96, 12), 256, 0, stream>>>(ff2w, 2359296,
                                                  wT + 4718592, WPL, 768, 3072);
  }

  for (int l = 0; l < 12; ++l) {
    bf16_t* wl = big ? wT + (size_t)l * WPL : wT;
    bf16_t* qkvT = wl;
    bf16_t* woT = wl + 1769472;
    bf16_t* ff1T = wl + 2359296;
    bf16_t* ff2T = wl + 4718592;

    if (l > 0)
      k_ln<<<8192, 192, 0, stream>>>(x, h, ln1_s + l * 768, ln1_b + l * 768);
    if (!big) {
      k_convT3<<<dim3(2, 24, 36), 256, 0, stream>>>(
          wq + (size_t)l * 589824, wk + (size_t)l * 589824,
          wv + (size_t)l * 589824, qkvT, 589824, 0);
      k_convT<<<dim3(24, 24, 1), 256, 0, stream>>>(wo + (size_t)l * 589824, 0,
                                                   woT, 0, 768, 768);
      k_convT<<<dim3(96, 24, 1), 256, 0, stream>>>(ff1w + (size_t)l * 2359296,
                                                   0, ff1T, 0, 3072, 768);
      k_convT<<<dim3(24, 96, 1), 256, 0, stream>>>(ff2w + (size_t)l * 2359296,
                                                   0, ff2T, 0, 768, 3072);
    }
    // QKV: M=8192 N=2304 K=768
    k_gemm<0><<<dim3(18, 64), 256, 0, stream>>>(h, 768, qkvT, 768, 768,
                                                nullptr, qkv, 2304, nullptr);
    // attention (log-softmax decomposition)
    k_lse<<<dim3(192, 8), 256, 0, stream>>>(qkv, lseb);
    k_attn2<<<192, 256, 0, stream>>>(qkv, lseb, ctx);
    // WO + residual
    k_gemm<1><<<dim3(6, 64), 256, 0, stream>>>(ctx, 768, woT, 768, 768, x,
                                               nullptr, 768, wo_b + l * 768);
    // FFN
    k_ln<<<8192, 192, 0, stream>>>(x, h, ln2_s + l * 768, ln2_b + l * 768);
    k_gemm<2><<<dim3(24, 64), 256, 0, stream>>>(h, 768, ff1T, 768, 768,
                                                nullptr, gbuf, 3072,
                                                ff1b + l * 3072);
    k_gemm<1><<<dim3(6, 64), 256, 0, stream>>>(gbuf, 3072, ff2T, 3072, 3072, x,
                                               nullptr, 768, ff2b + l * 768);
  }
  k_final<<<16, 192, 0, stream>>>(x, fln_s, fln_b, cw, cb, out);
}

// Round 9
// 4487.724 us; speedup vs baseline: 1.2655x; 1.0351x over previous
//
#include <hip/hip_runtime.h>
#include <hip/hip_bf16.h>
#include <math.h>

// Dims: B=16 S=512 D=768 H=12 DH=64 F=3072 LYR=12 NLAB=2; rows = B*S = 8192
typedef __bf16 bf16_t;
typedef __attribute__((ext_vector_type(8))) __bf16 bf16x8;
typedef __attribute__((ext_vector_type(4))) float f32x4;

typedef const __attribute__((address_space(1))) void av1_void;
typedef __attribute__((address_space(3))) void av3_void;

#define DEV static __device__ __forceinline__

DEV void gload16(const void* g, void* l) {
  __builtin_amdgcn_global_load_lds((av1_void*)g, (av3_void*)l, 16, 0, 0);
}

// ---- block reduction over 3 waves (block=192) ----
DEV float bsum3(float v, float* red) {
#pragma unroll
  for (int o = 32; o > 0; o >>= 1) v += __shfl_xor(v, o, 64);
  __syncthreads();
  if ((threadIdx.x & 63) == 0) red[threadIdx.x >> 6] = v;
  __syncthreads();
  return red[0] + red[1] + red[2];
}

// ---- embedding gather + emb-LN -> x (fp32), then ln1(layer0) -> h (bf16) ----
__global__ __launch_bounds__(192) void k_embed(
    const int* __restrict__ ids, const float* __restrict__ tok,
    const float* __restrict__ pos, const float* __restrict__ gam,
    const float* __restrict__ bet, const float* __restrict__ gam2,
    const float* __restrict__ bet2, float* __restrict__ x,
    bf16_t* __restrict__ h) {
  __shared__ float red[3];
  int row = blockIdx.x;          // b*512 + s
  int s = row & 511;
  int t = threadIdx.x;
  int id = ids[row];
  const float4 tv = *(const float4*)&tok[(size_t)id * 768 + t * 4];
  const float4 pv = *(const float4*)&pos[(size_t)s * 768 + t * 4];
  float v[4] = {tv.x + pv.x, tv.y + pv.y, tv.z + pv.z, tv.w + pv.w};
  float tot = bsum3(v[0] + v[1] + v[2] + v[3], red);
  float mu = tot * (1.f / 768.f);
  float sq = 0.f;
#pragma unroll
  for (int u = 0; u < 4; ++u) { float d = v[u] - mu; sq += d * d; }
  float var = bsum3(sq, red) * (1.f / 768.f);
  float rstd = rsqrtf(var + 1e-5f);
  const float4 g4 = *(const float4*)&gam[t * 4];
  const float4 b4 = *(const float4*)&bet[t * 4];
  float o[4];
  o[0] = (v[0] - mu) * rstd * g4.x + b4.x;
  o[1] = (v[1] - mu) * rstd * g4.y + b4.y;
  o[2] = (v[2] - mu) * rstd * g4.z + b4.z;
  o[3] = (v[3] - mu) * rstd * g4.w + b4.w;
  float4 ov = {o[0], o[1], o[2], o[3]};
  *(float4*)&x[(size_t)row * 768 + t * 4] = ov;
  // second LN (ln1 of layer 0) -> h
  float tot2 = bsum3(o[0] + o[1] + o[2] + o[3], red);
  float mu2 = tot2 * (1.f / 768.f);
  float sq2 = 0.f;
#pragma unroll
  for (int u = 0; u < 4; ++u) { float d = o[u] - mu2; sq2 += d * d; }
  float var2 = bsum3(sq2, red) * (1.f / 768.f);
  float rstd2 = rsqrtf(var2 + 1e-5f);
  const float4 G = *(const float4*)&gam2[t * 4];
  const float4 Bb = *(const float4*)&bet2[t * 4];
  union { bf16_t ob[4]; uint2 u2; } pk;
  pk.ob[0] = (bf16_t)((o[0] - mu2) * rstd2 * G.x + Bb.x);
  pk.ob[1] = (bf16_t)((o[1] - mu2) * rstd2 * G.y + Bb.y);
  pk.ob[2] = (bf16_t)((o[2] - mu2) * rstd2 * G.z + Bb.z);
  pk.ob[3] = (bf16_t)((o[3] - mu2) * rstd2 * G.w + Bb.w);
  *(uint2*)&h[(size_t)row * 768 + t * 4] = pk.u2;
}

// ---- LN: x (fp32) -> h (bf16) ----
__global__ __launch_bounds__(192) void k_ln(
    const float* __restrict__ xin, bf16_t* __restrict__ hout,
    const float* __restrict__ gam, const float* __restrict__ bet) {
  __shared__ float red[3];
  int row = blockIdx.x;
  int t = threadIdx.x;
  const float4 xv = *(const float4*)&xin[(size_t)row * 768 + t * 4];
  float v[4] = {xv.x, xv.y, xv.z, xv.w};
  float tot = bsum3(v[0] + v[1] + v[2] + v[3], red);
  float mu = tot * (1.f / 768.f);
  float sq = 0.f;
#pragma unroll
  for (int u = 0; u < 4; ++u) { float d = v[u] - mu; sq += d * d; }
  float var = bsum3(sq, red) * (1.f / 768.f);
  float rstd = rsqrtf(var + 1e-5f);
  const float4 g4 = *(const float4*)&gam[t * 4];
  const float4 b4 = *(const float4*)&bet[t * 4];
  union { bf16_t o[4]; uint2 u2; } pk;
  pk.o[0] = (bf16_t)((v[0] - mu) * rstd * g4.x + b4.x);
  pk.o[1] = (bf16_t)((v[1] - mu) * rstd * g4.y + b4.y);
  pk.o[2] = (bf16_t)((v[2] - mu) * rstd * g4.z + b4.z);
  pk.o[3] = (bf16_t)((v[3] - mu) * rstd * g4.w + b4.w);
  *(uint2*)&hout[(size_t)row * 768 + t * 4] = pk.u2;
}

// ---- transpose-convert fp32 [K][N] -> bf16 [N][K], per z-slice ----
__global__ __launch_bounds__(256) void k_convT(
    const float* __restrict__ in, size_t in_slice, bf16_t* __restrict__ out,
    size_t out_slice, int N, int K) {
  __shared__ float tbuf[32][33];
  int slice = blockIdx.z;
  const float* ip = in + (size_t)slice * in_slice;
  bf16_t* op = out + (size_t)slice * out_slice;
  int n0 = blockIdx.x * 32, k0 = blockIdx.y * 32;
  int c = threadIdx.x & 31, r8 = threadIdx.x >> 5;
#pragma unroll
  for (int i = 0; i < 4; ++i) {
    int rr = r8 + i * 8;
    tbuf[rr][c] = ip[(size_t)(k0 + rr) * N + n0 + c];
  }
  __syncthreads();
#pragma unroll
  for (int i = 0; i < 4; ++i) {
    int rr = r8 + i * 8;
    op[(size_t)(n0 + rr) * K + k0 + c] = (bf16_t)tbuf[c][rr];
  }
}

// ---- fused wq/wk/wv transpose-convert, NL layers: z = l*36 + which*12 + head
__global__ __launch_bounds__(256) void k_convT3(
    const float* __restrict__ wq, const float* __restrict__ wk,
    const float* __restrict__ wv, bf16_t* __restrict__ out,
    size_t in_lstride, size_t out_lstride) {
  __shared__ float tbuf[32][33];
  int z = blockIdx.z;
  int l = z / 36, r = z % 36;
  int which = r / 12, head = r % 12;
  const float* ip = (which == 0 ? wq : which == 1 ? wk : wv) +
                    (size_t)l * in_lstride + (size_t)head * 768 * 64;
  bf16_t* op = out + (size_t)l * out_lstride + (size_t)which * 768 * 768 +
               (size_t)head * 64 * 768;
  int n0 = blockIdx.x * 32, k0 = blockIdx.y * 32;   // N=64, K=768
  int c = threadIdx.x & 31, r8 = threadIdx.x >> 5;
#pragma unroll
  for (int i = 0; i < 4; ++i) {
    int rr = r8 + i * 8;
    tbuf[rr][c] = ip[(size_t)(k0 + rr) * 64 + n0 + c];
  }
  __syncthreads();
#pragma unroll
  for (int i = 0; i < 4; ++i) {
    int rr = r8 + i * 8;
    op[(size_t)(n0 + rr) * 768 + k0 + c] = (bf16_t)tbuf[c][rr];
  }
}

// ======================================================================
// 128x128 GEMM, m97 config: BK=32, SINGLE-buffered LDS (16KB -> ~5
// blocks/CU), 2 barriers per K-step; cross-block overlap hides drains.
// Both-sides XOR swizzle (row&3), XCD-aware 1D block swizzle.
// EPI 0: store bf16; EPI 1: Cf += C + bias; EPI 2: gelu(C+bias) -> bf16
// grid = gx*gy (1D), must be %8 == 0; K%32==0.
// ======================================================================
template <int EPI>
__global__ __launch_bounds__(256) void k_gemm(
    const bf16_t* __restrict__ A, int lda, const bf16_t* __restrict__ Bt,
    int ldb, int K, float* __restrict__ Cf, bf16_t* __restrict__ Cb, int ldc,
    const float* __restrict__ bias, int gx) {
  __shared__ __attribute__((aligned(16))) bf16_t As[128 * 32];
  __shared__ __attribute__((aligned(16))) bf16_t Bs[128 * 32];
  const int nwg = gridDim.x;
  const int bid = blockIdx.x;
  const int cpx = nwg >> 3;                 // grid % 8 == 0
  const int swz = (bid & 7) * cpx + (bid >> 3);
  const int bx = swz % gx, by = swz / gx;   // consecutive swz share row-panel
  const int m0 = by << 7, n0 = bx << 7;
  const int tid = threadIdx.x;
  const int lane = tid & 63, w = tid >> 6;
  const int wm = w >> 1, wn = w & 1;
  const int r = lane & 15, g4 = lane >> 4;

  f32x4 acc[4][4];
#pragma unroll
  for (int m = 0; m < 4; ++m)
#pragma unroll
    for (int n = 0; n < 4; ++n)
#pragma unroll
      for (int e = 0; e < 4; ++e) acc[m][n][e] = 0.f;

  const int NT = K >> 5;
  for (int t = 0; t < NT; ++t) {
    const int k0 = t << 5;
    // stage 128x32 A and B tiles (2 gload16/thread each)
#pragma unroll
    for (int u = 0; u < 2; ++u) {
      int s = u * 256 + tid;                // slot in [128 rows][4 chunks]
      int row = s >> 2;
      int c = (s & 3) ^ (row & 3);          // inverse-swizzled source chunk
      gload16(A + (size_t)(m0 + row) * lda + k0 + c * 8,
              (char*)As + (size_t)(u * 256 + (w << 6)) * 16);
    }
#pragma unroll
    for (int u = 0; u < 2; ++u) {
      int s = u * 256 + tid;
      int row = s >> 2;
      int c = (s & 3) ^ (row & 3);
      gload16(Bt + (size_t)(n0 + row) * ldb + k0 + c * 8,
              (char*)Bs + (size_t)(u * 256 + (w << 6)) * 16);
    }
    __syncthreads();                        // tiles ready (vmcnt drained)

    bf16x8 af[4], bb[4];
#pragma unroll
    for (int m = 0; m < 4; ++m) {
      int row = wm * 64 + m * 16 + r;
      af[m] = *(const bf16x8*)&As[row * 32 + ((g4 ^ (row & 3)) << 3)];
    }
#pragma unroll
    for (int n = 0; n < 4; ++n) {
      int row = wn * 64 + n * 16 + r;
      bb[n] = *(const bf16x8*)&Bs[row * 32 + ((g4 ^ (row & 3)) << 3)];
    }
#pragma unroll
    for (int m = 0; m < 4; ++m)
#pragma unroll
      for (int n = 0; n < 4; ++n)
        acc[m][n] = __builtin_amdgcn_mfma_f32_16x16x32_bf16(af[m], bb[n],
                                                            acc[m][n], 0, 0, 0);
    __syncthreads();                        // all reads done before restage
  }

#pragma unroll
  for (int m = 0; m < 4; ++m) {
#pragma unroll
    for (int n = 0; n < 4; ++n) {
      int col = n0 + wn * 64 + n * 16 + r;
      float bv = 0.f;
      if constexpr (EPI != 0) bv = bias[col];
#pragma unroll
      for (int j = 0; j < 4; ++j) {
        int row = m0 + wm * 64 + m * 16 + g4 * 4 + j;
        float v = acc[m][n][j];
        if constexpr (EPI == 0) {
          Cb[(size_t)row * ldc + col] = (bf16_t)v;
        } else if constexpr (EPI == 1) {
          size_t o = (size_t)row * ldc + col;
          Cf[o] += v + bv;
        } else {
          float tt = v + bv;
          float ge = 0.5f * tt * (1.f + erff(tt * 0.70710678118f));
          Cb[(size_t)row * ldc + col] = (bf16_t)ge;
        }
      }
    }
  }
}

// ---- lse[b,h,s] = logsumexp_t( q.k/8 ) ; 64 q-rows per block ----
__global__ __launch_bounds__(256) void k_lse(const bf16_t* __restrict__ qkv,
                                             float* __restrict__ lseb) {
  __shared__ __attribute__((aligned(16))) bf16_t Ks[512 * 64];
  __shared__ __attribute__((aligned(16))) bf16_t Qs[64 * 64];
  int bh = blockIdx.x;
  int b = bh / 12, hh = bh % 12;
  int s0 = blockIdx.y * 64;
  int tid = threadIdx.x, lane = tid & 63, w = tid >> 6;
  int r = lane & 15, g4 = lane >> 4;
  const bf16_t* kb = qkv + (size_t)b * 512 * 2304 + 768 + hh * 64;
  const bf16_t* qb = qkv + ((size_t)(b * 512 + s0)) * 2304 + hh * 64;
#pragma unroll
  for (int i = 0; i < 16; ++i) {
    int c = i * 256 + tid;
    gload16(kb + (size_t)(c >> 3) * 2304 + (c & 7) * 8,
            (char*)Ks + (size_t)(i * 256 + (w << 6)) * 16);
  }
#pragma unroll
  for (int i = 0; i < 2; ++i) {
    int c = i * 256 + tid;
    gload16(qb + (size_t)(c >> 3) * 2304 + (c & 7) * 8,
            (char*)Qs + (size_t)(i * 256 + (w << 6)) * 16);
  }
  __syncthreads();

  f32x4 acc[32];
#pragma unroll
  for (int n = 0; n < 32; ++n)
#pragma unroll
    for (int e = 0; e < 4; ++e) acc[n][e] = 0.f;

#pragma unroll
  for (int kk = 0; kk < 2; ++kk) {
    bf16x8 aq = *(const bf16x8*)&Qs[(w * 16 + r) * 64 + kk * 32 + g4 * 8];
#pragma unroll
    for (int n = 0; n < 32; ++n) {
      bf16x8 bk = *(const bf16x8*)&Ks[(n * 16 + r) * 64 + kk * 32 + g4 * 8];
      acc[n] = __builtin_amdgcn_mfma_f32_16x16x32_bf16(aq, bk, acc[n], 0, 0, 0);
    }
  }
#pragma unroll
  for (int j = 0; j < 4; ++j) {
    float mx = -1e30f;
#pragma unroll
    for (int n = 0; n < 32; ++n) mx = fmaxf(mx, acc[n][j] * 0.125f);
#pragma unroll
    for (int o = 1; o < 16; o <<= 1) mx = fmaxf(mx, __shfl_xor(mx, o, 64));
    float sm = 0.f;
#pragma unroll
    for (int n = 0; n < 32; ++n) sm += expf(acc[n][j] * 0.125f - mx);
#pragma unroll
    for (int o = 1; o < 16; o <<= 1) sm += __shfl_xor(sm, o, 64);
    if (r == 0)
      lseb[(size_t)bh * 512 + s0 + w * 16 + g4 * 4 + j] = mx + logf(sm);
  }
}

// ---- fused attn tail: M=K^TV/8 & sumv in LDS, then ctx = qM - lse*sumv ----
__global__ __launch_bounds__(256) void k_attn2(
    const bf16_t* __restrict__ qkv, const float* __restrict__ lseb,
    bf16_t* __restrict__ ctx) {
  __shared__ __attribute__((aligned(16))) char arena[65536];  // Ks+Vs | Qs
  __shared__ __attribute__((aligned(16))) bf16_t Mt[64 * 64];
  __shared__ float svs[64];
  bf16_t* Ks = (bf16_t*)arena;                 // [128][64] bf16 (16KB)
  float* Vs = (float*)(arena + 16384);         // [128][64] f32 (32KB)
  bf16_t* Qs = (bf16_t*)arena;                 // [512][64] bf16 (64KB), phase 2

  int bh = blockIdx.x;
  int b = bh / 12, hh = bh % 12;
  int tid = threadIdx.x, lane = tid & 63, w = tid >> 6;
  const bf16_t* kb = qkv + (size_t)b * 512 * 2304 + 768 + hh * 64;
  const bf16_t* vb = qkv + (size_t)b * 512 * 2304 + 1536 + hh * 64;
  const bf16_t* qb = qkv + (size_t)b * 512 * 2304 + hh * 64;

  // ---- phase 1: M = K^T V / 8 (64x64), sumv ----
  int e1 = lane, grp = w;                      // e1 over K-dim, grp over e2/16
  f32x4 macc[4];
#pragma unroll
  for (int jj = 0; jj < 4; ++jj)
#pragma unroll
    for (int e = 0; e < 4; ++e) macc[jj][e] = 0.f;
  float sv = 0.f;

  for (int t0 = 0; t0 < 512; t0 += 128) {
#pragma unroll
    for (int i = 0; i < 4; ++i) {
      int c = i * 256 + tid;
      gload16(kb + (size_t)(t0 + (c >> 3)) * 2304 + (c & 7) * 8,
              (char*)Ks + (size_t)(i * 256 + (w << 6)) * 16);
    }
#pragma unroll
    for (int i = 0; i < 4; ++i) {
      int c = i * 256 + tid;
      int row = c >> 3, col = (c & 7) * 8;
      bf16x8 raw = *(const bf16x8*)(vb + (size_t)(t0 + row) * 2304 + col);
      f32x4 v0, v1;
#pragma unroll
      for (int u = 0; u < 4; ++u) { v0[u] = (float)raw[u]; v1[u] = (float)raw[u + 4]; }
      *(f32x4*)&Vs[row * 64 + col] = v0;
      *(f32x4*)&Vs[row * 64 + col + 4] = v1;
    }
    __syncthreads();
    for (int tt = 0; tt < 128; ++tt) {
      float kv = (float)Ks[tt * 64 + e1];
#pragma unroll
      for (int jj = 0; jj < 4; ++jj) {
        f32x4 vv = *(const f32x4*)&Vs[tt * 64 + grp * 16 + jj * 4];
        macc[jj] += kv * vv;
      }
    }
    if (tid < 64) {
      for (int tt = 0; tt < 128; ++tt) sv += Vs[tt * 64 + tid];
    }
    __syncthreads();
  }
  // write M^T into LDS as bf16: Mt[e2][e1]
#pragma unroll
  for (int jj = 0; jj < 4; ++jj)
#pragma unroll
    for (int u = 0; u < 4; ++u)
      Mt[(grp * 16 + jj * 4 + u) * 64 + e1] = (bf16_t)(macc[jj][u] * 0.125f);
  if (tid < 64) svs[tid] = sv;
  __syncthreads();                              // arena free, Mt/svs ready

  // ---- phase 2: ctx = q.M - lse*sumv ----
  int r = lane & 15, g4 = lane >> 4;
#pragma unroll
  for (int i = 0; i < 16; ++i) {
    int c = i * 256 + tid;
    gload16(qb + (size_t)(c >> 3) * 2304 + (c & 7) * 8,
            (char*)Qs + (size_t)(i * 256 + (w << 6)) * 16);
  }
  __syncthreads();                              // Qs ready

  f32x4 acc[8][4];
#pragma unroll
  for (int m = 0; m < 8; ++m)
#pragma unroll
    for (int n = 0; n < 4; ++n)
#pragma unroll
      for (int e = 0; e < 4; ++e) acc[m][n][e] = 0.f;

#pragma unroll
  for (int kk = 0; kk < 2; ++kk) {
    bf16x8 bm[4];
#pragma unroll
    for (int n = 0; n < 4; ++n)
      bm[n] = *(const bf16x8*)&Mt[(n * 16 + r) * 64 + kk * 32 + g4 * 8];
#pragma unroll
    for (int m = 0; m < 8; ++m) {
      bf16x8 aq = *(const bf16x8*)&Qs[(w * 128 + m * 16 + r) * 64 + kk * 32 + g4 * 8];
#pragma unroll
      for (int n = 0; n < 4; ++n)
        acc[m][n] = __builtin_amdgcn_mfma_f32_16x16x32_bf16(aq, bm[n], acc[m][n], 0, 0, 0);
    }
  }
#pragma unroll
  for (int m = 0; m < 8; ++m) {
#pragma unroll
    for (int n = 0; n < 4; ++n) {
      int col = n * 16 + r;
      float svv = svs[col];
#pragma unroll
      for (int j = 0; j < 4; ++j) {
        int s = w * 128 + m * 16 + g4 * 4 + j;
        float lv = lseb[(size_t)bh * 512 + s];
        float val = acc[m][n][j] - lv * svv;
        ctx[((size_t)(b * 512 + s)) * 768 + hh * 64 + col] = (bf16_t)val;
      }
    }
  }
}

// ---- final LN (row s=0 per batch) + classifier ----
__global__ __launch_bounds__(192) void k_final(
    const float* __restrict__ x, const float* __restrict__ gam,
    const float* __restrict__ bet, const float* __restrict__ cw,
    const float* __restrict__ cb, float* __restrict__ out) {
  __shared__ float red[3];
  int b = blockIdx.x, t = threadIdx.x;
  const float* xr = x + (size_t)b * 512 * 768;
  const float4 xv = *(const float4*)&xr[t * 4];
  float v[4] = {xv.x, xv.y, xv.z, xv.w};
  float tot = bsum3(v[0] + v[1] + v[2] + v[3], red);
  float mu = tot * (1.f / 768.f);
  float sq = 0.f;
#pragma unroll
  for (int u = 0; u < 4; ++u) { float d = v[u] - mu; sq += d * d; }
  float var = bsum3(sq, red) * (1.f / 768.f);
  float rstd = rsqrtf(var + 1e-5f);
  const float4 g4 = *(const float4*)&gam[t * 4];
  const float4 b4 = *(const float4*)&bet[t * 4];
  float nv[4];
  nv[0] = (v[0] - mu) * rstd * g4.x + b4.x;
  nv[1] = (v[1] - mu) * rstd * g4.y + b4.y;
  nv[2] = (v[2] - mu) * rstd * g4.z + b4.z;
  nv[3] = (v[3] - mu) * rstd * g4.w + b4.w;
  const float4 wa = *(const float4*)&cw[t * 8];
  const float4 wb = *(const float4*)&cw[t * 8 + 4];
  float d0 = nv[0] * wa.x + nv[1] * wa.z + nv[2] * wb.x + nv[3] * wb.z;
  float d1 = nv[0] * wa.y + nv[1] * wa.w + nv[2] * wb.y + nv[3] * wb.w;
  d0 = bsum3(d0, red);
  d1 = bsum3(d1, red);
  if (t == 0) {
    out[b * 2 + 0] = d0 + cb[0];
    out[b * 2 + 1] = d1 + cb[1];
  }
}

// ---- workspace layout ----
static constexpr size_t OFF_X = 0;                                  // f32 8192x768
static constexpr size_t OFF_H = OFF_X + 8192ull * 768 * 4;          // bf16 8192x768
static constexpr size_t OFF_QG = OFF_H + 8192ull * 768 * 2;         // bf16 arena (qkv | gelu)
static constexpr size_t OFF_CTX = OFF_QG + 8192ull * 3072 * 2;      // bf16 8192x768
static constexpr size_t OFF_LSE = OFF_CTX + 8192ull * 768 * 2;      // f32 192*512
static constexpr size_t OFF_W = OFF_LSE + 192ull * 512 * 4;         // bf16 weights
static constexpr size_t WPL = 7077888;                              // elems per layer
static constexpr size_t WS_SMALL = OFF_W + WPL * 2;                 // 1-layer buffer
static constexpr size_t WS_BIG = OFF_W + 12ull * WPL * 2;           // all layers

extern "C" void kernel_launch(void* const* d_in, const int* in_sizes, int n_in,
                              void* d_out, int out_size, void* d_ws,
                              size_t ws_size, hipStream_t stream) {
  const int* ids = (const int*)d_in[0];
  const float* tok = (const float*)d_in[1];
  const float* pos = (const float*)d_in[2];
  const float* eln_s = (const float*)d_in[3];
  const float* eln_b = (const float*)d_in[4];
  const float* wq = (const float*)d_in[5];
  const float* wk = (const float*)d_in[6];
  const float* wv = (const float*)d_in[7];
  const float* wo = (const float*)d_in[8];
  const float* wo_b = (const float*)d_in[9];
  const float* ln1_s = (const float*)d_in[10];
  const float* ln1_b = (const float*)d_in[11];
  const float* ln2_s = (const float*)d_in[12];
  const float* ln2_b = (const float*)d_in[13];
  const float* ff1w = (const float*)d_in[14];
  const float* ff1b = (const float*)d_in[15];
  const float* ff2w = (const float*)d_in[16];
  const float* ff2b = (const float*)d_in[17];
  const float* fln_s = (const float*)d_in[18];
  const float* fln_b = (const float*)d_in[19];
  const float* cw = (const float*)d_in[20];
  const float* cb = (const float*)d_in[21];
  float* out = (float*)d_out;

  if (ws_size < WS_SMALL) return;
  const bool big = ws_size >= WS_BIG;

  char* ws = (char*)d_ws;
  float* x = (float*)(ws + OFF_X);
  bf16_t* h = (bf16_t*)(ws + OFF_H);
  bf16_t* qkv = (bf16_t*)(ws + OFF_QG);
  bf16_t* gbuf = (bf16_t*)(ws + OFF_QG);
  bf16_t* ctx = (bf16_t*)(ws + OFF_CTX);
  float* lseb = (float*)(ws + OFF_LSE);
  bf16_t* wT = (bf16_t*)(ws + OFF_W);

  // embedding + emb-LN + ln1(layer0)
  k_embed<<<8192, 192, 0, stream>>>(ids, tok, pos, eln_s, eln_b,
                                    ln1_s, ln1_b, x, h);

  if (big) {
    // convert ALL layers' weights upfront: 4 launches
    k_convT3<<<dim3(2, 24, 432), 256, 0, stream>>>(wq, wk, wv, wT,
                                                   589824, WPL);
    k_convT<<<dim3(24, 24, 12), 256, 0, stream>>>(wo, 589824,
                                                  wT + 1769472, WPL, 768, 768);
    k_convT<<<dim3(96, 24, 12), 256, 0, stream>>>(ff1w, 2359296,
                                                  wT + 2359296, WPL, 3072, 768);
    k_convT<<<dim3(24, 96, 12), 256, 0, stream>>>(ff2w, 2359296,
                                                  wT + 4718592, WPL, 768, 3072);
  }

  for (int l = 0; l < 12; ++l) {
    bf16_t* wl = big ? wT + (size_t)l * WPL : wT;
    bf16_t* qkvT = wl;
    bf16_t* woT = wl + 1769472;
    bf16_t* ff1T = wl + 2359296;
    bf16_t* ff2T = wl + 4718592;

    if (l > 0)
      k_ln<<<8192, 192, 0, stream>>>(x, h, ln1_s + l * 768, ln1_b + l * 768);
    if (!big) {
      k_convT3<<<dim3(2, 24, 36), 256, 0, stream>>>(
          wq + (size_t)l * 589824, wk + (size_t)l * 589824,
          wv + (size_t)l * 589824, qkvT, 589824, 0);
      k_convT<<<dim3(24, 24, 1), 256, 0, stream>>>(wo + (size_t)l * 589824, 0,
                                                   woT, 0, 768, 768);
      k_convT<<<dim3(96, 24, 1), 256, 0, stream>>>(ff1w + (size_t)l * 2359296,
                                                   0, ff1T, 0, 3072, 768);
      k_convT<<<dim3(24, 96, 1), 256, 0, stream>>>(ff2w + (size_t)l * 2359296,
                                                   0, ff2T, 0, 768, 3072);
    }
    // QKV: M=8192 N=2304 K=768 -> grid 18*64=1152
    k_gemm<0><<<1152, 256, 0, stream>>>(h, 768, qkvT, 768, 768,
                                        nullptr, qkv, 2304, nullptr, 18);
    // attention (log-softmax decomposition)
    k_lse<<<dim3(192, 8), 256, 0, stream>>>(qkv, lseb);
    k_attn2<<<192, 256, 0, stream>>>(qkv, lseb, ctx);
    // WO + residual: grid 6*64=384
    k_gemm<1><<<384, 256, 0, stream>>>(ctx, 768, woT, 768, 768, x,
                                       nullptr, 768, wo_b + l * 768, 6);
    // FFN
    k_ln<<<8192, 192, 0, stream>>>(x, h, ln2_s + l * 768, ln2_b + l * 768);
    // FF1: grid 24*64=1536
    k_gemm<2><<<1536, 256, 0, stream>>>(h, 768, ff1T, 768, 768,
                                        nullptr, gbuf, 3072,
                                        ff1b + l * 3072, 24);
    // FF2: grid 6*64=384
    k_gemm<1><<<384, 256, 0, stream>>>(gbuf, 3072, ff2T, 3072, 3072, x,
                                       nullptr, 768, ff2b + l * 768, 6);
  }
  k_final<<<16, 192, 0, stream>>>(x, fln_s, fln_b, cw, cb, out);
}

// Round 10
// 4205.882 us; speedup vs baseline: 1.3503x; 1.0670x over previous
//
#include <hip/hip_runtime.h>
#include <hip/hip_bf16.h>
#include <math.h>

// Dims: B=16 S=512 D=768 H=12 DH=64 F=3072 LYR=12 NLAB=2; rows = B*S = 8192
typedef __bf16 bf16_t;
typedef __attribute__((ext_vector_type(8))) __bf16 bf16x8;
typedef __attribute__((ext_vector_type(4))) float f32x4;

typedef const __attribute__((address_space(1))) void av1_void;
typedef __attribute__((address_space(3))) void av3_void;

#define DEV static __device__ __forceinline__

DEV void gload16(const void* g, void* l) {
  __builtin_amdgcn_global_load_lds((av1_void*)g, (av3_void*)l, 16, 0, 0);
}

// ---- block reduction over 3 waves (block=192) ----
DEV float bsum3(float v, float* red) {
#pragma unroll
  for (int o = 32; o > 0; o >>= 1) v += __shfl_xor(v, o, 64);
  __syncthreads();
  if ((threadIdx.x & 63) == 0) red[threadIdx.x >> 6] = v;
  __syncthreads();
  return red[0] + red[1] + red[2];
}

// ---- embedding gather + emb-LN -> x (fp32), then ln1(layer0) -> h (bf16) ----
__global__ __launch_bounds__(192) void k_embed(
    const int* __restrict__ ids, const float* __restrict__ tok,
    const float* __restrict__ pos, const float* __restrict__ gam,
    const float* __restrict__ bet, const float* __restrict__ gam2,
    const float* __restrict__ bet2, float* __restrict__ x,
    bf16_t* __restrict__ h) {
  __shared__ float red[3];
  int row = blockIdx.x;          // b*512 + s
  int s = row & 511;
  int t = threadIdx.x;
  int id = ids[row];
  const float4 tv = *(const float4*)&tok[(size_t)id * 768 + t * 4];
  const float4 pv = *(const float4*)&pos[(size_t)s * 768 + t * 4];
  float v[4] = {tv.x + pv.x, tv.y + pv.y, tv.z + pv.z, tv.w + pv.w};
  float tot = bsum3(v[0] + v[1] + v[2] + v[3], red);
  float mu = tot * (1.f / 768.f);
  float sq = 0.f;
#pragma unroll
  for (int u = 0; u < 4; ++u) { float d = v[u] - mu; sq += d * d; }
  float var = bsum3(sq, red) * (1.f / 768.f);
  float rstd = rsqrtf(var + 1e-5f);
  const float4 g4 = *(const float4*)&gam[t * 4];
  const float4 b4 = *(const float4*)&bet[t * 4];
  float o[4];
  o[0] = (v[0] - mu) * rstd * g4.x + b4.x;
  o[1] = (v[1] - mu) * rstd * g4.y + b4.y;
  o[2] = (v[2] - mu) * rstd * g4.z + b4.z;
  o[3] = (v[3] - mu) * rstd * g4.w + b4.w;
  float4 ov = {o[0], o[1], o[2], o[3]};
  *(float4*)&x[(size_t)row * 768 + t * 4] = ov;
  // second LN (ln1 of layer 0) -> h
  float tot2 = bsum3(o[0] + o[1] + o[2] + o[3], red);
  float mu2 = tot2 * (1.f / 768.f);
  float sq2 = 0.f;
#pragma unroll
  for (int u = 0; u < 4; ++u) { float d = o[u] - mu2; sq2 += d * d; }
  float var2 = bsum3(sq2, red) * (1.f / 768.f);
  float rstd2 = rsqrtf(var2 + 1e-5f);
  const float4 G = *(const float4*)&gam2[t * 4];
  const float4 Bb = *(const float4*)&bet2[t * 4];
  union { bf16_t ob[4]; uint2 u2; } pk;
  pk.ob[0] = (bf16_t)((o[0] - mu2) * rstd2 * G.x + Bb.x);
  pk.ob[1] = (bf16_t)((o[1] - mu2) * rstd2 * G.y + Bb.y);
  pk.ob[2] = (bf16_t)((o[2] - mu2) * rstd2 * G.z + Bb.z);
  pk.ob[3] = (bf16_t)((o[3] - mu2) * rstd2 * G.w + Bb.w);
  *(uint2*)&h[(size_t)row * 768 + t * 4] = pk.u2;
}

// ---- LN: x (fp32) -> h (bf16) ----
__global__ __launch_bounds__(192) void k_ln(
    const float* __restrict__ xin, bf16_t* __restrict__ hout,
    const float* __restrict__ gam, const float* __restrict__ bet) {
  __shared__ float red[3];
  int row = blockIdx.x;
  int t = threadIdx.x;
  const float4 xv = *(const float4*)&xin[(size_t)row * 768 + t * 4];
  float v[4] = {xv.x, xv.y, xv.z, xv.w};
  float tot = bsum3(v[0] + v[1] + v[2] + v[3], red);
  float mu = tot * (1.f / 768.f);
  float sq = 0.f;
#pragma unroll
  for (int u = 0; u < 4; ++u) { float d = v[u] - mu; sq += d * d; }
  float var = bsum3(sq, red) * (1.f / 768.f);
  float rstd = rsqrtf(var + 1e-5f);
  const float4 g4 = *(const float4*)&gam[t * 4];
  const float4 b4 = *(const float4*)&bet[t * 4];
  union { bf16_t o[4]; uint2 u2; } pk;
  pk.o[0] = (bf16_t)((v[0] - mu) * rstd * g4.x + b4.x);
  pk.o[1] = (bf16_t)((v[1] - mu) * rstd * g4.y + b4.y);
  pk.o[2] = (bf16_t)((v[2] - mu) * rstd * g4.z + b4.z);
  pk.o[3] = (bf16_t)((v[3] - mu) * rstd * g4.w + b4.w);
  *(uint2*)&hout[(size_t)row * 768 + t * 4] = pk.u2;
}

// ---- transpose-convert fp32 [K][N] -> bf16 [N][K], per z-slice ----
__global__ __launch_bounds__(256) void k_convT(
    const float* __restrict__ in, size_t in_slice, bf16_t* __restrict__ out,
    size_t out_slice, int N, int K) {
  __shared__ float tbuf[32][33];
  int slice = blockIdx.z;
  const float* ip = in + (size_t)slice * in_slice;
  bf16_t* op = out + (size_t)slice * out_slice;
  int n0 = blockIdx.x * 32, k0 = blockIdx.y * 32;
  int c = threadIdx.x & 31, r8 = threadIdx.x >> 5;
#pragma unroll
  for (int i = 0; i < 4; ++i) {
    int rr = r8 + i * 8;
    tbuf[rr][c] = ip[(size_t)(k0 + rr) * N + n0 + c];
  }
  __syncthreads();
#pragma unroll
  for (int i = 0; i < 4; ++i) {
    int rr = r8 + i * 8;
    op[(size_t)(n0 + rr) * K + k0 + c] = (bf16_t)tbuf[c][rr];
  }
}

// ---- fused wq/wk/wv transpose-convert, NL layers: z = l*36 + which*12 + head
__global__ __launch_bounds__(256) void k_convT3(
    const float* __restrict__ wq, const float* __restrict__ wk,
    const float* __restrict__ wv, bf16_t* __restrict__ out,
    size_t in_lstride, size_t out_lstride) {
  __shared__ float tbuf[32][33];
  int z = blockIdx.z;
  int l = z / 36, r = z % 36;
  int which = r / 12, head = r % 12;
  const float* ip = (which == 0 ? wq : which == 1 ? wk : wv) +
                    (size_t)l * in_lstride + (size_t)head * 768 * 64;
  bf16_t* op = out + (size_t)l * out_lstride + (size_t)which * 768 * 768 +
               (size_t)head * 64 * 768;
  int n0 = blockIdx.x * 32, k0 = blockIdx.y * 32;   // N=64, K=768
  int c = threadIdx.x & 31, r8 = threadIdx.x >> 5;
#pragma unroll
  for (int i = 0; i < 4; ++i) {
    int rr = r8 + i * 8;
    tbuf[rr][c] = ip[(size_t)(k0 + rr) * 64 + n0 + c];
  }
  __syncthreads();
#pragma unroll
  for (int i = 0; i < 4; ++i) {
    int rr = r8 + i * 8;
    op[(size_t)(n0 + rr) * 768 + k0 + c] = (bf16_t)tbuf[c][rr];
  }
}

// ======================================================================
// 128x128 GEMM: BK=64, SINGLE-buffered LDS (32KB -> 5 blocks/CU),
// 2 barriers per K-step (32 MFMA per step), hoisted staging pointers,
// row&7 XOR swizzle (conflict-free, round-2 verified), XCD block swizzle.
// EPI 0: store bf16; EPI 1: Cf += C + bias; EPI 2: gelu(C+bias) -> bf16
// grid = gx*gy (1D), must be %8 == 0; K%64==0.
// ======================================================================
template <int EPI>
__global__ __launch_bounds__(256) void k_gemm(
    const bf16_t* __restrict__ A, int lda, const bf16_t* __restrict__ Bt,
    int ldb, int K, float* __restrict__ Cf, bf16_t* __restrict__ Cb, int ldc,
    const float* __restrict__ bias, int gx) {
  __shared__ __attribute__((aligned(16))) bf16_t As[128 * 64];
  __shared__ __attribute__((aligned(16))) bf16_t Bs[128 * 64];
  const int nwg = gridDim.x;
  const int bid = blockIdx.x;
  const int cpx = nwg >> 3;                 // grid % 8 == 0
  const int swz = (bid & 7) * cpx + (bid >> 3);
  const int bx = swz % gx, by = swz / gx;   // consecutive swz share row-panel
  const int m0 = by << 7, n0 = bx << 7;
  const int tid = threadIdx.x;
  const int lane = tid & 63, w = tid >> 6;
  const int wm = w >> 1, wn = w & 1;
  const int r = lane & 15, g4 = lane >> 4;

  f32x4 acc[4][4];
#pragma unroll
  for (int m = 0; m < 4; ++m)
#pragma unroll
    for (int n = 0; n < 4; ++n)
#pragma unroll
      for (int e = 0; e < 4; ++e) acc[m][n][e] = 0.f;

  // hoisted staging pointers: slot s -> row = s>>3, chunk c = (s&7)^(row&7)
  const bf16_t* pa[4];
  const bf16_t* pb[4];
  char* la[4];
  char* lb[4];
#pragma unroll
  for (int u = 0; u < 4; ++u) {
    int s = u * 256 + tid;                  // 16B slot in [128 rows][8 chunks]
    int row = s >> 3;
    int c = (s & 7) ^ (row & 7);
    pa[u] = A + (size_t)(m0 + row) * lda + c * 8;
    pb[u] = Bt + (size_t)(n0 + row) * ldb + c * 8;
    la[u] = (char*)As + (size_t)(u * 256 + (w << 6)) * 16;  // wave-uniform base
    lb[u] = (char*)Bs + (size_t)(u * 256 + (w << 6)) * 16;
  }

  const int NT = K >> 6;
  for (int t = 0; t < NT; ++t) {
    const int k0 = t << 6;
#pragma unroll
    for (int u = 0; u < 4; ++u) gload16(pa[u] + k0, la[u]);
#pragma unroll
    for (int u = 0; u < 4; ++u) gload16(pb[u] + k0, lb[u]);
    __syncthreads();                        // tiles ready (vmcnt drained)

#pragma unroll
    for (int kk = 0; kk < 2; ++kk) {
      bf16x8 af[4], bb[4];
#pragma unroll
      for (int m = 0; m < 4; ++m) {
        int row = wm * 64 + m * 16 + r;
        af[m] = *(const bf16x8*)&As[row * 64 +
                                    (((kk << 2) + g4) ^ (row & 7)) * 8];
      }
#pragma unroll
      for (int n = 0; n < 4; ++n) {
        int row = wn * 64 + n * 16 + r;
        bb[n] = *(const bf16x8*)&Bs[row * 64 +
                                    (((kk << 2) + g4) ^ (row & 7)) * 8];
      }
#pragma unroll
      for (int m = 0; m < 4; ++m)
#pragma unroll
        for (int n = 0; n < 4; ++n)
          acc[m][n] = __builtin_amdgcn_mfma_f32_16x16x32_bf16(af[m], bb[n],
                                                              acc[m][n], 0, 0, 0);
    }
    __syncthreads();                        // all reads done before restage
  }

#pragma unroll
  for (int m = 0; m < 4; ++m) {
#pragma unroll
    for (int n = 0; n < 4; ++n) {
      int col = n0 + wn * 64 + n * 16 + r;
      float bv = 0.f;
      if constexpr (EPI != 0) bv = bias[col];
#pragma unroll
      for (int j = 0; j < 4; ++j) {
        int row = m0 + wm * 64 + m * 16 + g4 * 4 + j;
        float v = acc[m][n][j];
        if constexpr (EPI == 0) {
          Cb[(size_t)row * ldc + col] = (bf16_t)v;
        } else if constexpr (EPI == 1) {
          size_t o = (size_t)row * ldc + col;
          Cf[o] += v + bv;
        } else {
          float tt = v + bv;
          float ge = 0.5f * tt * (1.f + erff(tt * 0.70710678118f));
          Cb[(size_t)row * ldc + col] = (bf16_t)ge;
        }
      }
    }
  }
}

// ---- lse[b,h,s] = logsumexp_t( q.k/8 ) ; 64 q-rows per block ----
__global__ __launch_bounds__(256) void k_lse(const bf16_t* __restrict__ qkv,
                                             float* __restrict__ lseb) {
  __shared__ __attribute__((aligned(16))) bf16_t Ks[512 * 64];
  __shared__ __attribute__((aligned(16))) bf16_t Qs[64 * 64];
  int bh = blockIdx.x;
  int b = bh / 12, hh = bh % 12;
  int s0 = blockIdx.y * 64;
  int tid = threadIdx.x, lane = tid & 63, w = tid >> 6;
  int r = lane & 15, g4 = lane >> 4;
  const bf16_t* kb = qkv + (size_t)b * 512 * 2304 + 768 + hh * 64;
  const bf16_t* qb = qkv + ((size_t)(b * 512 + s0)) * 2304 + hh * 64;
#pragma unroll
  for (int i = 0; i < 16; ++i) {
    int c = i * 256 + tid;
    gload16(kb + (size_t)(c >> 3) * 2304 + (c & 7) * 8,
            (char*)Ks + (size_t)(i * 256 + (w << 6)) * 16);
  }
#pragma unroll
  for (int i = 0; i < 2; ++i) {
    int c = i * 256 + tid;
    gload16(qb + (size_t)(c >> 3) * 2304 + (c & 7) * 8,
            (char*)Qs + (size_t)(i * 256 + (w << 6)) * 16);
  }
  __syncthreads();

  f32x4 acc[32];
#pragma unroll
  for (int n = 0; n < 32; ++n)
#pragma unroll
    for (int e = 0; e < 4; ++e) acc[n][e] = 0.f;

#pragma unroll
  for (int kk = 0; kk < 2; ++kk) {
    bf16x8 aq = *(const bf16x8*)&Qs[(w * 16 + r) * 64 + kk * 32 + g4 * 8];
#pragma unroll
    for (int n = 0; n < 32; ++n) {
      bf16x8 bk = *(const bf16x8*)&Ks[(n * 16 + r) * 64 + kk * 32 + g4 * 8];
      acc[n] = __builtin_amdgcn_mfma_f32_16x16x32_bf16(aq, bk, acc[n], 0, 0, 0);
    }
  }
#pragma unroll
  for (int j = 0; j < 4; ++j) {
    float mx = -1e30f;
#pragma unroll
    for (int n = 0; n < 32; ++n) mx = fmaxf(mx, acc[n][j] * 0.125f);
#pragma unroll
    for (int o = 1; o < 16; o <<= 1) mx = fmaxf(mx, __shfl_xor(mx, o, 64));
    float sm = 0.f;
#pragma unroll
    for (int n = 0; n < 32; ++n) sm += expf(acc[n][j] * 0.125f - mx);
#pragma unroll
    for (int o = 1; o < 16; o <<= 1) sm += __shfl_xor(sm, o, 64);
    if (r == 0)
      lseb[(size_t)bh * 512 + s0 + w * 16 + g4 * 4 + j] = mx + logf(sm);
  }
}

// ---- fused attn tail: M=K^TV/8 & sumv in LDS, then ctx = qM - lse*sumv ----
__global__ __launch_bounds__(256) void k_attn2(
    const bf16_t* __restrict__ qkv, const float* __restrict__ lseb,
    bf16_t* __restrict__ ctx) {
  __shared__ __attribute__((aligned(16))) char arena[65536];  // Ks+Vs | Qs
  __shared__ __attribute__((aligned(16))) bf16_t Mt[64 * 64];
  __shared__ float svs[64];
  bf16_t* Ks = (bf16_t*)arena;                 // [128][64] bf16 (16KB)
  float* Vs = (float*)(arena + 16384);         // [128][64] f32 (32KB)
  bf16_t* Qs = (bf16_t*)arena;                 // [512][64] bf16 (64KB), phase 2

  int bh = blockIdx.x;
  int b = bh / 12, hh = bh % 12;
  int tid = threadIdx.x, lane = tid & 63, w = tid >> 6;
  const bf16_t* kb = qkv + (size_t)b * 512 * 2304 + 768 + hh * 64;
  const bf16_t* vb = qkv + (size_t)b * 512 * 2304 + 1536 + hh * 64;
  const bf16_t* qb = qkv + (size_t)b * 512 * 2304 + hh * 64;

  // ---- phase 1: M = K^T V / 8 (64x64), sumv ----
  int e1 = lane, grp = w;                      // e1 over K-dim, grp over e2/16
  f32x4 macc[4];
#pragma unroll
  for (int jj = 0; jj < 4; ++jj)
#pragma unroll
    for (int e = 0; e < 4; ++e) macc[jj][e] = 0.f;
  float sv = 0.f;

  for (int t0 = 0; t0 < 512; t0 += 128) {
#pragma unroll
    for (int i = 0; i < 4; ++i) {
      int c = i * 256 + tid;
      gload16(kb + (size_t)(t0 + (c >> 3)) * 2304 + (c & 7) * 8,
              (char*)Ks + (size_t)(i * 256 + (w << 6)) * 16);
    }
#pragma unroll
    for (int i = 0; i < 4; ++i) {
      int c = i * 256 + tid;
      int row = c >> 3, col = (c & 7) * 8;
      bf16x8 raw = *(const bf16x8*)(vb + (size_t)(t0 + row) * 2304 + col);
      f32x4 v0, v1;
#pragma unroll
      for (int u = 0; u < 4; ++u) { v0[u] = (float)raw[u]; v1[u] = (float)raw[u + 4]; }
      *(f32x4*)&Vs[row * 64 + col] = v0;
      *(f32x4*)&Vs[row * 64 + col + 4] = v1;
    }
    __syncthreads();
    for (int tt = 0; tt < 128; ++tt) {
      float kv = (float)Ks[tt * 64 + e1];
#pragma unroll
      for (int jj = 0; jj < 4; ++jj) {
        f32x4 vv = *(const f32x4*)&Vs[tt * 64 + grp * 16 + jj * 4];
        macc[jj] += kv * vv;
      }
    }
    if (tid < 64) {
      for (int tt = 0; tt < 128; ++tt) sv += Vs[tt * 64 + tid];
    }
    __syncthreads();
  }
  // write M^T into LDS as bf16: Mt[e2][e1]
#pragma unroll
  for (int jj = 0; jj < 4; ++jj)
#pragma unroll
    for (int u = 0; u < 4; ++u)
      Mt[(grp * 16 + jj * 4 + u) * 64 + e1] = (bf16_t)(macc[jj][u] * 0.125f);
  if (tid < 64) svs[tid] = sv;
  __syncthreads();                              // arena free, Mt/svs ready

  // ---- phase 2: ctx = q.M - lse*sumv ----
  int r = lane & 15, g4 = lane >> 4;
#pragma unroll
  for (int i = 0; i < 16; ++i) {
    int c = i * 256 + tid;
    gload16(qb + (size_t)(c >> 3) * 2304 + (c & 7) * 8,
            (char*)Qs + (size_t)(i * 256 + (w << 6)) * 16);
  }
  __syncthreads();                              // Qs ready

  f32x4 acc[8][4];
#pragma unroll
  for (int m = 0; m < 8; ++m)
#pragma unroll
    for (int n = 0; n < 4; ++n)
#pragma unroll
      for (int e = 0; e < 4; ++e) acc[m][n][e] = 0.f;

#pragma unroll
  for (int kk = 0; kk < 2; ++kk) {
    bf16x8 bm[4];
#pragma unroll
    for (int n = 0; n < 4; ++n)
      bm[n] = *(const bf16x8*)&Mt[(n * 16 + r) * 64 + kk * 32 + g4 * 8];
#pragma unroll
    for (int m = 0; m < 8; ++m) {
      bf16x8 aq = *(const bf16x8*)&Qs[(w * 128 + m * 16 + r) * 64 + kk * 32 + g4 * 8];
#pragma unroll
      for (int n = 0; n < 4; ++n)
        acc[m][n] = __builtin_amdgcn_mfma_f32_16x16x32_bf16(aq, bm[n], acc[m][n], 0, 0, 0);
    }
  }
#pragma unroll
  for (int m = 0; m < 8; ++m) {
#pragma unroll
    for (int n = 0; n < 4; ++n) {
      int col = n * 16 + r;
      float svv = svs[col];
#pragma unroll
      for (int j = 0; j < 4; ++j) {
        int s = w * 128 + m * 16 + g4 * 4 + j;
        float lv = lseb[(size_t)bh * 512 + s];
        float val = acc[m][n][j] - lv * svv;
        ctx[((size_t)(b * 512 + s)) * 768 + hh * 64 + col] = (bf16_t)val;
      }
    }
  }
}

// ---- final LN (row s=0 per batch) + classifier ----
__global__ __launch_bounds__(192) void k_final(
    const float* __restrict__ x, const float* __restrict__ gam,
    const float* __restrict__ bet, const float* __restrict__ cw,
    const float* __restrict__ cb, float* __restrict__ out) {
  __shared__ float red[3];
  int b = blockIdx.x, t = threadIdx.x;
  const float* xr = x + (size_t)b * 512 * 768;
  const float4 xv = *(const float4*)&xr[t * 4];
  float v[4] = {xv.x, xv.y, xv.z, xv.w};
  float tot = bsum3(v[0] + v[1] + v[2] + v[3], red);
  float mu = tot * (1.f / 768.f);
  float sq = 0.f;
#pragma unroll
  for (int u = 0; u < 4; ++u) { float d = v[u] - mu; sq += d * d; }
  float var = bsum3(sq, red) * (1.f / 768.f);
  float rstd = rsqrtf(var + 1e-5f);
  const float4 g4 = *(const float4*)&gam[t * 4];
  const float4 b4 = *(const float4*)&bet[t * 4];
  float nv[4];
  nv[0] = (v[0] - mu) * rstd * g4.x + b4.x;
  nv[1] = (v[1] - mu) * rstd * g4.y + b4.y;
  nv[2] = (v[2] - mu) * rstd * g4.z + b4.z;
  nv[3] = (v[3] - mu) * rstd * g4.w + b4.w;
  const float4 wa = *(const float4*)&cw[t * 8];
  const float4 wb = *(const float4*)&cw[t * 8 + 4];
  float d0 = nv[0] * wa.x + nv[1] * wa.z + nv[2] * wb.x + nv[3] * wb.z;
  float d1 = nv[0] * wa.y + nv[1] * wa.w + nv[2] * wb.y + nv[3] * wb.w;
  d0 = bsum3(d0, red);
  d1 = bsum3(d1, red);
  if (t == 0) {
    out[b * 2 + 0] = d0 + cb[0];
    out[b * 2 + 1] = d1 + cb[1];
  }
}

// ---- workspace layout ----
static constexpr size_t OFF_X = 0;                                  // f32 8192x768
static constexpr size_t OFF_H = OFF_X + 8192ull * 768 * 4;          // bf16 8192x768
static constexpr size_t OFF_QG = OFF_H + 8192ull * 768 * 2;         // bf16 arena (qkv | gelu)
static constexpr size_t OFF_CTX = OFF_QG + 8192ull * 3072 * 2;      // bf16 8192x768
static constexpr size_t OFF_LSE = OFF_CTX + 8192ull * 768 * 2;      // f32 192*512
static constexpr size_t OFF_W = OFF_LSE + 192ull * 512 * 4;         // bf16 weights
static constexpr size_t WPL = 7077888;                              // elems per layer
static constexpr size_t WS_SMALL = OFF_W + WPL * 2;                 // 1-layer buffer
static constexpr size_t WS_BIG = OFF_W + 12ull * WPL * 2;           // all layers

extern "C" void kernel_launch(void* const* d_in, const int* in_sizes, int n_in,
                              void* d_out, int out_size, void* d_ws,
                              size_t ws_size, hipStream_t stream) {
  const int* ids = (const int*)d_in[0];
  const float* tok = (const float*)d_in[1];
  const float* pos = (const float*)d_in[2];
  const float* eln_s = (const float*)d_in[3];
  const float* eln_b = (const float*)d_in[4];
  const float* wq = (const float*)d_in[5];
  const float* wk = (const float*)d_in[6];
  const float* wv = (const float*)d_in[7];
  const float* wo = (const float*)d_in[8];
  const float* wo_b = (const float*)d_in[9];
  const float* ln1_s = (const float*)d_in[10];
  const float* ln1_b = (const float*)d_in[11];
  const float* ln2_s = (const float*)d_in[12];
  const float* ln2_b = (const float*)d_in[13];
  const float* ff1w = (const float*)d_in[14];
  const float* ff1b = (const float*)d_in[15];
  const float* ff2w = (const float*)d_in[16];
  const float* ff2b = (const float*)d_in[17];
  const float* fln_s = (const float*)d_in[18];
  const float* fln_b = (const float*)d_in[19];
  const float* cw = (const float*)d_in[20];
  const float* cb = (const float*)d_in[21];
  float* out = (float*)d_out;

  if (ws_size < WS_SMALL) return;
  const bool big = ws_size >= WS_BIG;

  char* ws = (char*)d_ws;
  float* x = (float*)(ws + OFF_X);
  bf16_t* h = (bf16_t*)(ws + OFF_H);
  bf16_t* qkv = (bf16_t*)(ws + OFF_QG);
  bf16_t* gbuf = (bf16_t*)(ws + OFF_QG);
  bf16_t* ctx = (bf16_t*)(ws + OFF_CTX);
  float* lseb = (float*)(ws + OFF_LSE);
  bf16_t* wT = (bf16_t*)(ws + OFF_W);

  // embedding + emb-LN + ln1(layer0)
  k_embed<<<8192, 192, 0, stream>>>(ids, tok, pos, eln_s, eln_b,
                                    ln1_s, ln1_b, x, h);

  if (big) {
    // convert ALL layers' weights upfront: 4 launches
    k_convT3<<<dim3(2, 24, 432), 256, 0, stream>>>(wq, wk, wv, wT,
                                                   589824, WPL);
    k_convT<<<dim3(24, 24, 12), 256, 0, stream>>>(wo, 589824,
                                                  wT + 1769472, WPL, 768, 768);
    k_convT<<<dim3(96, 24, 12), 256, 0, stream>>>(ff1w, 2359296,
                                                  wT + 2359296, WPL, 3072, 768);
    k_convT<<<dim3(24, 96, 12), 256, 0, stream>>>(ff2w, 2359296,
                                                  wT + 4718592, WPL, 768, 3072);
  }

  for (int l = 0; l < 12; ++l) {
    bf16_t* wl = big ? wT + (size_t)l * WPL : wT;
    bf16_t* qkvT = wl;
    bf16_t* woT = wl + 1769472;
    bf16_t* ff1T = wl + 2359296;
    bf16_t* ff2T = wl + 4718592;

    if (l > 0)
      k_ln<<<8192, 192, 0, stream>>>(x, h, ln1_s + l * 768, ln1_b + l * 768);
    if (!big) {
      k_convT3<<<dim3(2, 24, 36), 256, 0, stream>>>(
          wq + (size_t)l * 589824, wk + (size_t)l * 589824,
          wv + (size_t)l * 589824, qkvT, 589824, 0);
      k_convT<<<dim3(24, 24, 1), 256, 0, stream>>>(wo + (size_t)l * 589824, 0,
                                                   woT, 0, 768, 768);
      k_convT<<<dim3(96, 24, 1), 256, 0, stream>>>(ff1w + (size_t)l * 2359296,
                                                   0, ff1T, 0, 3072, 768);
      k_convT<<<dim3(24, 96, 1), 256, 0, stream>>>(ff2w + (size_t)l * 2359296,
                                                   0, ff2T, 0, 768, 3072);
    }
    // QKV: M=8192 N=2304 K=768 -> grid 18*64=1152
    k_gemm<0><<<1152, 256, 0, stream>>>(h, 768, qkvT, 768, 768,
                                        nullptr, qkv, 2304, nullptr, 18);
    // attention (log-softmax decomposition)
    k_lse<<<dim3(192, 8), 256, 0, stream>>>(qkv, lseb);
    k_attn2<<<192, 256, 0, stream>>>(qkv, lseb, ctx);
    // WO + residual: grid 6*64=384
    k_gemm<1><<<384, 256, 0, stream>>>(ctx, 768, woT, 768, 768, x,
                                       nullptr, 768, wo_b + l * 768, 6);
    // FFN
    k_ln<<<8192, 192, 0, stream>>>(x, h, ln2_s + l * 768, ln2_b + l * 768);
    // FF1: grid 24*64=1536
    k_gemm<2><<<1536, 256, 0, stream>>>(h, 768, ff1T, 768, 768,
                                        nullptr, gbuf, 3072,
                                        ff1b + l * 3072, 24);
    // FF2: grid 6*64=384
    k_gemm<1><<<384, 256, 0, stream>>>(gbuf, 3072, ff2T, 3072, 3072, x,
                                       nullptr, 768, ff2b + l * 768, 6);
  }
  k_final<<<16, 192, 0, stream>>>(x, fln_s, fln_b, cw, cb, out);
}

// Round 11
// 4175.148 us; speedup vs baseline: 1.3602x; 1.0074x over previous
//
#include <hip/hip_runtime.h>
#include <hip/hip_bf16.h>
#include <math.h>

// Dims: B=16 S=512 D=768 H=12 DH=64 F=3072 LYR=12 NLAB=2; rows = B*S = 8192
typedef __bf16 bf16_t;
typedef __attribute__((ext_vector_type(8))) __bf16 bf16x8;
typedef __attribute__((ext_vector_type(4))) float f32x4;

typedef const __attribute__((address_space(1))) void av1_void;
typedef __attribute__((address_space(3))) void av3_void;

#define DEV static __device__ __forceinline__

DEV void gload16(const void* g, void* l) {
  __builtin_amdgcn_global_load_lds((av1_void*)g, (av3_void*)l, 16, 0, 0);
}

// ---- block reduction over 3 waves (block=192) ----
DEV float bsum3(float v, float* red) {
#pragma unroll
  for (int o = 32; o > 0; o >>= 1) v += __shfl_xor(v, o, 64);
  __syncthreads();
  if ((threadIdx.x & 63) == 0) red[threadIdx.x >> 6] = v;
  __syncthreads();
  return red[0] + red[1] + red[2];
}

// ---- embedding gather + emb-LN -> x (fp32), then ln1(layer0) -> h (bf16) ----
__global__ __launch_bounds__(192) void k_embed(
    const int* __restrict__ ids, const float* __restrict__ tok,
    const float* __restrict__ pos, const float* __restrict__ gam,
    const float* __restrict__ bet, const float* __restrict__ gam2,
    const float* __restrict__ bet2, float* __restrict__ x,
    bf16_t* __restrict__ h) {
  __shared__ float red[3];
  int row = blockIdx.x;          // b*512 + s
  int s = row & 511;
  int t = threadIdx.x;
  int id = ids[row];
  const float4 tv = *(const float4*)&tok[(size_t)id * 768 + t * 4];
  const float4 pv = *(const float4*)&pos[(size_t)s * 768 + t * 4];
  float v[4] = {tv.x + pv.x, tv.y + pv.y, tv.z + pv.z, tv.w + pv.w};
  float tot = bsum3(v[0] + v[1] + v[2] + v[3], red);
  float mu = tot * (1.f / 768.f);
  float sq = 0.f;
#pragma unroll
  for (int u = 0; u < 4; ++u) { float d = v[u] - mu; sq += d * d; }
  float var = bsum3(sq, red) * (1.f / 768.f);
  float rstd = rsqrtf(var + 1e-5f);
  const float4 g4 = *(const float4*)&gam[t * 4];
  const float4 b4 = *(const float4*)&bet[t * 4];
  float o[4];
  o[0] = (v[0] - mu) * rstd * g4.x + b4.x;
  o[1] = (v[1] - mu) * rstd * g4.y + b4.y;
  o[2] = (v[2] - mu) * rstd * g4.z + b4.z;
  o[3] = (v[3] - mu) * rstd * g4.w + b4.w;
  float4 ov = {o[0], o[1], o[2], o[3]};
  *(float4*)&x[(size_t)row * 768 + t * 4] = ov;
  // second LN (ln1 of layer 0) -> h
  float tot2 = bsum3(o[0] + o[1] + o[2] + o[3], red);
  float mu2 = tot2 * (1.f / 768.f);
  float sq2 = 0.f;
#pragma unroll
  for (int u = 0; u < 4; ++u) { float d = o[u] - mu2; sq2 += d * d; }
  float var2 = bsum3(sq2, red) * (1.f / 768.f);
  float rstd2 = rsqrtf(var2 + 1e-5f);
  const float4 G = *(const float4*)&gam2[t * 4];
  const float4 Bb = *(const float4*)&bet2[t * 4];
  union { bf16_t ob[4]; uint2 u2; } pk;
  pk.ob[0] = (bf16_t)((o[0] - mu2) * rstd2 * G.x + Bb.x);
  pk.ob[1] = (bf16_t)((o[1] - mu2) * rstd2 * G.y + Bb.y);
  pk.ob[2] = (bf16_t)((o[2] - mu2) * rstd2 * G.z + Bb.z);
  pk.ob[3] = (bf16_t)((o[3] - mu2) * rstd2 * G.w + Bb.w);
  *(uint2*)&h[(size_t)row * 768 + t * 4] = pk.u2;
}

// ---- LN: x (fp32) -> h (bf16) ----
__global__ __launch_bounds__(192) void k_ln(
    const float* __restrict__ xin, bf16_t* __restrict__ hout,
    const float* __restrict__ gam, const float* __restrict__ bet) {
  __shared__ float red[3];
  int row = blockIdx.x;
  int t = threadIdx.x;
  const float4 xv = *(const float4*)&xin[(size_t)row * 768 + t * 4];
  float v[4] = {xv.x, xv.y, xv.z, xv.w};
  float tot = bsum3(v[0] + v[1] + v[2] + v[3], red);
  float mu = tot * (1.f / 768.f);
  float sq = 0.f;
#pragma unroll
  for (int u = 0; u < 4; ++u) { float d = v[u] - mu; sq += d * d; }
  float var = bsum3(sq, red) * (1.f / 768.f);
  float rstd = rsqrtf(var + 1e-5f);
  const float4 g4 = *(const float4*)&gam[t * 4];
  const float4 b4 = *(const float4*)&bet[t * 4];
  union { bf16_t o[4]; uint2 u2; } pk;
  pk.o[0] = (bf16_t)((v[0] - mu) * rstd * g4.x + b4.x);
  pk.o[1] = (bf16_t)((v[1] - mu) * rstd * g4.y + b4.y);
  pk.o[2] = (bf16_t)((v[2] - mu) * rstd * g4.z + b4.z);
  pk.o[3] = (bf16_t)((v[3] - mu) * rstd * g4.w + b4.w);
  *(uint2*)&hout[(size_t)row * 768 + t * 4] = pk.u2;
}

// ---- transpose-convert fp32 [K][N] -> bf16 [N][K], per z-slice ----
__global__ __launch_bounds__(256) void k_convT(
    const float* __restrict__ in, size_t in_slice, bf16_t* __restrict__ out,
    size_t out_slice, int N, int K) {
  __shared__ float tbuf[32][33];
  int slice = blockIdx.z;
  const float* ip = in + (size_t)slice * in_slice;
  bf16_t* op = out + (size_t)slice * out_slice;
  int n0 = blockIdx.x * 32, k0 = blockIdx.y * 32;
  int c = threadIdx.x & 31, r8 = threadIdx.x >> 5;
#pragma unroll
  for (int i = 0; i < 4; ++i) {
    int rr = r8 + i * 8;
    tbuf[rr][c] = ip[(size_t)(k0 + rr) * N + n0 + c];
  }
  __syncthreads();
#pragma unroll
  for (int i = 0; i < 4; ++i) {
    int rr = r8 + i * 8;
    op[(size_t)(n0 + rr) * K + k0 + c] = (bf16_t)tbuf[c][rr];
  }
}

// ---- fused wq/wk/wv transpose-convert, NL layers: z = l*36 + which*12 + head
__global__ __launch_bounds__(256) void k_convT3(
    const float* __restrict__ wq, const float* __restrict__ wk,
    const float* __restrict__ wv, bf16_t* __restrict__ out,
    size_t in_lstride, size_t out_lstride) {
  __shared__ float tbuf[32][33];
  int z = blockIdx.z;
  int l = z / 36, r = z % 36;
  int which = r / 12, head = r % 12;
  const float* ip = (which == 0 ? wq : which == 1 ? wk : wv) +
                    (size_t)l * in_lstride + (size_t)head * 768 * 64;
  bf16_t* op = out + (size_t)l * out_lstride + (size_t)which * 768 * 768 +
               (size_t)head * 64 * 768;
  int n0 = blockIdx.x * 32, k0 = blockIdx.y * 32;   // N=64, K=768
  int c = threadIdx.x & 31, r8 = threadIdx.x >> 5;
#pragma unroll
  for (int i = 0; i < 4; ++i) {
    int rr = r8 + i * 8;
    tbuf[rr][c] = ip[(size_t)(k0 + rr) * 64 + n0 + c];
  }
  __syncthreads();
#pragma unroll
  for (int i = 0; i < 4; ++i) {
    int rr = r8 + i * 8;
    op[(size_t)(n0 + rr) * 768 + k0 + c] = (bf16_t)tbuf[c][rr];
  }
}

// ======================================================================
// 128x128 GEMM: BK=32, THREE-buffer LDS (48KB -> 3 blocks/CU), counted
// vmcnt(4) (2-step prefetch flight, loads cross barriers), raw s_barrier,
// (row>>1)&3 XOR swizzle (2 lanes/bank = free), XCD block swizzle.
// Per step: {vmcnt(4); barrier; COMPUTE(t,buf t%3); barrier; STAGE(t+2)}.
// EPI 0: store bf16; EPI 1: Cf += C + bias; EPI 2: gelu(C+bias) -> bf16
// grid = gx*gy (1D), must be %8 == 0; K%32==0, K>=64.
// ======================================================================
template <int EPI>
__global__ __launch_bounds__(256) void k_gemm(
    const bf16_t* __restrict__ A, int lda, const bf16_t* __restrict__ Bt,
    int ldb, int K, float* __restrict__ Cf, bf16_t* __restrict__ Cb, int ldc,
    const float* __restrict__ bias, int gx) {
  __shared__ __attribute__((aligned(16))) bf16_t As[3][128 * 32];
  __shared__ __attribute__((aligned(16))) bf16_t Bs[3][128 * 32];
  const int nwg = gridDim.x;
  const int bid = blockIdx.x;
  const int cpx = nwg >> 3;                 // grid % 8 == 0
  const int swz = (bid & 7) * cpx + (bid >> 3);
  const int bx = swz % gx, by = swz / gx;   // consecutive swz share row-panel
  const int m0 = by << 7, n0 = bx << 7;
  const int tid = threadIdx.x;
  const int lane = tid & 63, w = tid >> 6;
  const int wm = w >> 1, wn = w & 1;
  const int r = lane & 15, g4 = lane >> 4;

  f32x4 acc[4][4];
#pragma unroll
  for (int m = 0; m < 4; ++m)
#pragma unroll
    for (int n = 0; n < 4; ++n)
#pragma unroll
      for (int e = 0; e < 4; ++e) acc[m][n][e] = 0.f;

  // hoisted staging pointers: slot s -> row = s>>2, chunk c = (s&3)^((row>>1)&3)
  const bf16_t* pa[2];
  const bf16_t* pb[2];
  uint32_t lo[2];
#pragma unroll
  for (int u = 0; u < 2; ++u) {
    int s = u * 256 + tid;                  // 16B slot in [128 rows][4 chunks]
    int row = s >> 2;
    int c = (s & 3) ^ ((row >> 1) & 3);
    pa[u] = A + (size_t)(m0 + row) * lda + c * 8;
    pb[u] = Bt + (size_t)(n0 + row) * ldb + c * 8;
    lo[u] = (uint32_t)(u * 256 + (w << 6)) * 16;      // wave-uniform + lane*16
  }

  const int NT = K >> 5;
  auto STAGE = [&](int t, int bufi) {
    int k0 = (t < NT ? t : NT - 1) << 5;    // clamped dummy tail stage
#pragma unroll
    for (int u = 0; u < 2; ++u) gload16(pa[u] + k0, (char*)&As[bufi][0] + lo[u]);
#pragma unroll
    for (int u = 0; u < 2; ++u) gload16(pb[u] + k0, (char*)&Bs[bufi][0] + lo[u]);
  };

  STAGE(0, 0);
  STAGE(1, 1);
  int bi = 0;                               // compute buffer = t%3
  int si = 2;                               // stage buffer = (t+2)%3
  const int co = (g4 ^ ((r >> 1) & 3)) << 3;  // swizzled chunk offset (elems)
  for (int t = 0; t < NT; ++t) {
    asm volatile("s_waitcnt vmcnt(4)" ::: "memory");  // own loads(t) landed
    asm volatile("s_barrier" ::: "memory");           // all waves' loads(t) landed
    bf16x8 af[4], bb[4];
#pragma unroll
    for (int m = 0; m < 4; ++m) {
      int row = wm * 64 + m * 16 + r;
      af[m] = *(const bf16x8*)&As[bi][row * 32 + co];
    }
#pragma unroll
    for (int n = 0; n < 4; ++n) {
      int row = wn * 64 + n * 16 + r;
      bb[n] = *(const bf16x8*)&Bs[bi][row * 32 + co];
    }
#pragma unroll
    for (int m = 0; m < 4; ++m)
#pragma unroll
      for (int n = 0; n < 4; ++n)
        acc[m][n] = __builtin_amdgcn_mfma_f32_16x16x32_bf16(af[m], bb[n],
                                                            acc[m][n], 0, 0, 0);
    asm volatile("s_barrier" ::: "memory");           // all done reading (t-1)+... 
    STAGE(t + 2, si);                       // writes buf (t+2)%3 == (t-1)%3: dead
    si = bi;
    bi = (bi == 2) ? 0 : bi + 1;
  }
  asm volatile("s_waitcnt vmcnt(0)" ::: "memory");    // drain tail dummies

#pragma unroll
  for (int m = 0; m < 4; ++m) {
#pragma unroll
    for (int n = 0; n < 4; ++n) {
      int col = n0 + wn * 64 + n * 16 + r;
      float bv = 0.f;
      if constexpr (EPI != 0) bv = bias[col];
#pragma unroll
      for (int j = 0; j < 4; ++j) {
        int row = m0 + wm * 64 + m * 16 + g4 * 4 + j;
        float v = acc[m][n][j];
        if constexpr (EPI == 0) {
          Cb[(size_t)row * ldc + col] = (bf16_t)v;
        } else if constexpr (EPI == 1) {
          size_t o = (size_t)row * ldc + col;
          Cf[o] += v + bv;
        } else {
          float tt = v + bv;
          float ge = 0.5f * tt * (1.f + erff(tt * 0.70710678118f));
          Cb[(size_t)row * ldc + col] = (bf16_t)ge;
        }
      }
    }
  }
}

// ---- lse[b,h,s] = logsumexp_t( q.k/8 ) ; 64 q-rows per block ----
__global__ __launch_bounds__(256) void k_lse(const bf16_t* __restrict__ qkv,
                                             float* __restrict__ lseb) {
  __shared__ __attribute__((aligned(16))) bf16_t Ks[512 * 64];
  __shared__ __attribute__((aligned(16))) bf16_t Qs[64 * 64];
  int bh = blockIdx.x;
  int b = bh / 12, hh = bh % 12;
  int s0 = blockIdx.y * 64;
  int tid = threadIdx.x, lane = tid & 63, w = tid >> 6;
  int r = lane & 15, g4 = lane >> 4;
  const bf16_t* kb = qkv + (size_t)b * 512 * 2304 + 768 + hh * 64;
  const bf16_t* qb = qkv + ((size_t)(b * 512 + s0)) * 2304 + hh * 64;
#pragma unroll
  for (int i = 0; i < 16; ++i) {
    int c = i * 256 + tid;
    gload16(kb + (size_t)(c >> 3) * 2304 + (c & 7) * 8,
            (char*)Ks + (size_t)(i * 256 + (w << 6)) * 16);
  }
#pragma unroll
  for (int i = 0; i < 2; ++i) {
    int c = i * 256 + tid;
    gload16(qb + (size_t)(c >> 3) * 2304 + (c & 7) * 8,
            (char*)Qs + (size_t)(i * 256 + (w << 6)) * 16);
  }
  __syncthreads();

  f32x4 acc[32];
#pragma unroll
  for (int n = 0; n < 32; ++n)
#pragma unroll
    for (int e = 0; e < 4; ++e) acc[n][e] = 0.f;

#pragma unroll
  for (int kk = 0; kk < 2; ++kk) {
    bf16x8 aq = *(const bf16x8*)&Qs[(w * 16 + r) * 64 + kk * 32 + g4 * 8];
#pragma unroll
    for (int n = 0; n < 32; ++n) {
      bf16x8 bk = *(const bf16x8*)&Ks[(n * 16 + r) * 64 + kk * 32 + g4 * 8];
      acc[n] = __builtin_amdgcn_mfma_f32_16x16x32_bf16(aq, bk, acc[n], 0, 0, 0);
    }
  }
#pragma unroll
  for (int j = 0; j < 4; ++j) {
    float mx = -1e30f;
#pragma unroll
    for (int n = 0; n < 32; ++n) mx = fmaxf(mx, acc[n][j] * 0.125f);
#pragma unroll
    for (int o = 1; o < 16; o <<= 1) mx = fmaxf(mx, __shfl_xor(mx, o, 64));
    float sm = 0.f;
#pragma unroll
    for (int n = 0; n < 32; ++n) sm += expf(acc[n][j] * 0.125f - mx);
#pragma unroll
    for (int o = 1; o < 16; o <<= 1) sm += __shfl_xor(sm, o, 64);
    if (r == 0)
      lseb[(size_t)bh * 512 + s0 + w * 16 + g4 * 4 + j] = mx + logf(sm);
  }
}

// ---- fused attn tail: M=K^TV/8 & sumv in LDS, then ctx = qM - lse*sumv ----
__global__ __launch_bounds__(256) void k_attn2(
    const bf16_t* __restrict__ qkv, const float* __restrict__ lseb,
    bf16_t* __restrict__ ctx) {
  __shared__ __attribute__((aligned(16))) char arena[65536];  // Ks+Vs | Qs
  __shared__ __attribute__((aligned(16))) bf16_t Mt[64 * 64];
  __shared__ float svs[64];
  bf16_t* Ks = (bf16_t*)arena;                 // [128][64] bf16 (16KB)
  float* Vs = (float*)(arena + 16384);         // [128][64] f32 (32KB)
  bf16_t* Qs = (bf16_t*)arena;                 // [512][64] bf16 (64KB), phase 2

  int bh = blockIdx.x;
  int b = bh / 12, hh = bh % 12;
  int tid = threadIdx.x, lane = tid & 63, w = tid >> 6;
  const bf16_t* kb = qkv + (size_t)b * 512 * 2304 + 768 + hh * 64;
  const bf16_t* vb = qkv + (size_t)b * 512 * 2304 + 1536 + hh * 64;
  const bf16_t* qb = qkv + (size_t)b * 512 * 2304 + hh * 64;

  // ---- phase 1: M = K^T V / 8 (64x64), sumv ----
  int e1 = lane, grp = w;                      // e1 over K-dim, grp over e2/16
  f32x4 macc[4];
#pragma unroll
  for (int jj = 0; jj < 4; ++jj)
#pragma unroll
    for (int e = 0; e < 4; ++e) macc[jj][e] = 0.f;
  float sv = 0.f;

  for (int t0 = 0; t0 < 512; t0 += 128) {
#pragma unroll
    for (int i = 0; i < 4; ++i) {
      int c = i * 256 + tid;
      gload16(kb + (size_t)(t0 + (c >> 3)) * 2304 + (c & 7) * 8,
              (char*)Ks + (size_t)(i * 256 + (w << 6)) * 16);
    }
#pragma unroll
    for (int i = 0; i < 4; ++i) {
      int c = i * 256 + tid;
      int row = c >> 3, col = (c & 7) * 8;
      bf16x8 raw = *(const bf16x8*)(vb + (size_t)(t0 + row) * 2304 + col);
      f32x4 v0, v1;
#pragma unroll
      for (int u = 0; u < 4; ++u) { v0[u] = (float)raw[u]; v1[u] = (float)raw[u + 4]; }
      *(f32x4*)&Vs[row * 64 + col] = v0;
      *(f32x4*)&Vs[row * 64 + col + 4] = v1;
    }
    __syncthreads();
    for (int tt = 0; tt < 128; ++tt) {
      float kv = (float)Ks[tt * 64 + e1];
#pragma unroll
      for (int jj = 0; jj < 4; ++jj) {
        f32x4 vv = *(const f32x4*)&Vs[tt * 64 + grp * 16 + jj * 4];
        macc[jj] += kv * vv;
      }
    }
    if (tid < 64) {
      for (int tt = 0; tt < 128; ++tt) sv += Vs[tt * 64 + tid];
    }
    __syncthreads();
  }
  // write M^T into LDS as bf16: Mt[e2][e1]
#pragma unroll
  for (int jj = 0; jj < 4; ++jj)
#pragma unroll
    for (int u = 0; u < 4; ++u)
      Mt[(grp * 16 + jj * 4 + u) * 64 + e1] = (bf16_t)(macc[jj][u] * 0.125f);
  if (tid < 64) svs[tid] = sv;
  __syncthreads();                              // arena free, Mt/svs ready

  // ---- phase 2: ctx = q.M - lse*sumv ----
  int r = lane & 15, g4 = lane >> 4;
#pragma unroll
  for (int i = 0; i < 16; ++i) {
    int c = i * 256 + tid;
    gload16(qb + (size_t)(c >> 3) * 2304 + (c & 7) * 8,
            (char*)Qs + (size_t)(i * 256 + (w << 6)) * 16);
  }
  __syncthreads();                              // Qs ready

  f32x4 acc[8][4];
#pragma unroll
  for (int m = 0; m < 8; ++m)
#pragma unroll
    for (int n = 0; n < 4; ++n)
#pragma unroll
      for (int e = 0; e < 4; ++e) acc[m][n][e] = 0.f;

#pragma unroll
  for (int kk = 0; kk < 2; ++kk) {
    bf16x8 bm[4];
#pragma unroll
    for (int n = 0; n < 4; ++n)
      bm[n] = *(const bf16x8*)&Mt[(n * 16 + r) * 64 + kk * 32 + g4 * 8];
#pragma unroll
    for (int m = 0; m < 8; ++m) {
      bf16x8 aq = *(const bf16x8*)&Qs[(w * 128 + m * 16 + r) * 64 + kk * 32 + g4 * 8];
#pragma unroll
      for (int n = 0; n < 4; ++n)
        acc[m][n] = __builtin_amdgcn_mfma_f32_16x16x32_bf16(aq, bm[n], acc[m][n], 0, 0, 0);
    }
  }
#pragma unroll
  for (int m = 0; m < 8; ++m) {
#pragma unroll
    for (int n = 0; n < 4; ++n) {
      int col = n * 16 + r;
      float svv = svs[col];
#pragma unroll
      for (int j = 0; j < 4; ++j) {
        int s = w * 128 + m * 16 + g4 * 4 + j;
        float lv = lseb[(size_t)bh * 512 + s];
        float val = acc[m][n][j] - lv * svv;
        ctx[((size_t)(b * 512 + s)) * 768 + hh * 64 + col] = (bf16_t)val;
      }
    }
  }
}

// ---- final LN (row s=0 per batch) + classifier ----
__global__ __launch_bounds__(192) void k_final(
    const float* __restrict__ x, const float* __restrict__ gam,
    const float* __restrict__ bet, const float* __restrict__ cw,
    const float* __restrict__ cb, float* __restrict__ out) {
  __shared__ float red[3];
  int b = blockIdx.x, t = threadIdx.x;
  const float* xr = x + (size_t)b * 512 * 768;
  const float4 xv = *(const float4*)&xr[t * 4];
  float v[4] = {xv.x, xv.y, xv.z, xv.w};
  float tot = bsum3(v[0] + v[1] + v[2] + v[3], red);
  float mu = tot * (1.f / 768.f);
  float sq = 0.f;
#pragma unroll
  for (int u = 0; u < 4; ++u) { float d = v[u] - mu; sq += d * d; }
  float var = bsum3(sq, red) * (1.f / 768.f);
  float rstd = rsqrtf(var + 1e-5f);
  const float4 g4 = *(const float4*)&gam[t * 4];
  const float4 b4 = *(const float4*)&bet[t * 4];
  float nv[4];
  nv[0] = (v[0] - mu) * rstd * g4.x + b4.x;
  nv[1] = (v[1] - mu) * rstd * g4.y + b4.y;
  nv[2] = (v[2] - mu) * rstd * g4.z + b4.z;
  nv[3] = (v[3] - mu) * rstd * g4.w + b4.w;
  const float4 wa = *(const float4*)&cw[t * 8];
  const float4 wb = *(const float4*)&cw[t * 8 + 4];
  float d0 = nv[0] * wa.x + nv[1] * wa.z + nv[2] * wb.x + nv[3] * wb.z;
  float d1 = nv[0] * wa.y + nv[1] * wa.w + nv[2] * wb.y + nv[3] * wb.w;
  d0 = bsum3(d0, red);
  d1 = bsum3(d1, red);
  if (t == 0) {
    out[b * 2 + 0] = d0 + cb[0];
    out[b * 2 + 1] = d1 + cb[1];
  }
}

// ---- workspace layout ----
static constexpr size_t OFF_X = 0;                                  // f32 8192x768
static constexpr size_t OFF_H = OFF_X + 8192ull * 768 * 4;          // bf16 8192x768
static constexpr size_t OFF_QG = OFF_H + 8192ull * 768 * 2;         // bf16 arena (qkv | gelu)
static constexpr size_t OFF_CTX = OFF_QG + 8192ull * 3072 * 2;      // bf16 8192x768
static constexpr size_t OFF_LSE = OFF_CTX + 8192ull * 768 * 2;      // f32 192*512
static constexpr size_t OFF_W = OFF_LSE + 192ull * 512 * 4;         // bf16 weights
static constexpr size_t WPL = 7077888;                              // elems per layer
static constexpr size_t WS_SMALL = OFF_W + WPL * 2;                 // 1-layer buffer
static constexpr size_t WS_BIG = OFF_W + 12ull * WPL * 2;           // all layers

extern "C" void kernel_launch(void* const* d_in, const int* in_sizes, int n_in,
                              void* d_out, int out_size, void* d_ws,
                              size_t ws_size, hipStream_t stream) {
  const int* ids = (const int*)d_in[0];
  const float* tok = (const float*)d_in[1];
  const float* pos = (const float*)d_in[2];
  const float* eln_s = (const float*)d_in[3];
  const float* eln_b = (const float*)d_in[4];
  const float* wq = (const float*)d_in[5];
  const float* wk = (const float*)d_in[6];
  const float* wv = (const float*)d_in[7];
  const float* wo = (const float*)d_in[8];
  const float* wo_b = (const float*)d_in[9];
  const float* ln1_s = (const float*)d_in[10];
  const float* ln1_b = (const float*)d_in[11];
  const float* ln2_s = (const float*)d_in[12];
  const float* ln2_b = (const float*)d_in[13];
  const float* ff1w = (const float*)d_in[14];
  const float* ff1b = (const float*)d_in[15];
  const float* ff2w = (const float*)d_in[16];
  const float* ff2b = (const float*)d_in[17];
  const float* fln_s = (const float*)d_in[18];
  const float* fln_b = (const float*)d_in[19];
  const float* cw = (const float*)d_in[20];
  const float* cb = (const float*)d_in[21];
  float* out = (float*)d_out;

  if (ws_size < WS_SMALL) return;
  const bool big = ws_size >= WS_BIG;

  char* ws = (char*)d_ws;
  float* x = (float*)(ws + OFF_X);
  bf16_t* h = (bf16_t*)(ws + OFF_H);
  bf16_t* qkv = (bf16_t*)(ws + OFF_QG);
  bf16_t* gbuf = (bf16_t*)(ws + OFF_QG);
  bf16_t* ctx = (bf16_t*)(ws + OFF_CTX);
  float* lseb = (float*)(ws + OFF_LSE);
  bf16_t* wT = (bf16_t*)(ws + OFF_W);

  // embedding + emb-LN + ln1(layer0)
  k_embed<<<8192, 192, 0, stream>>>(ids, tok, pos, eln_s, eln_b,
                                    ln1_s, ln1_b, x, h);

  if (big) {
    // convert ALL layers' weights upfront: 4 launches
    k_convT3<<<dim3(2, 24, 432), 256, 0, stream>>>(wq, wk, wv, wT,
                                                   589824, WPL);
    k_convT<<<dim3(24, 24, 12), 256, 0, stream>>>(wo, 589824,
                                                  wT + 1769472, WPL, 768, 768);
    k_convT<<<dim3(96, 24, 12), 256, 0, stream>>>(ff1w, 2359296,
                                                  wT + 2359296, WPL, 3072, 768);
    k_convT<<<dim3(24, 96, 12), 256, 0, stream>>>(ff2w, 2359296,
                                                  wT + 4718592, WPL, 768, 3072);
  }

  for (int l = 0; l < 12; ++l) {
    bf16_t* wl = big ? wT + (size_t)l * WPL : wT;
    bf16_t* qkvT = wl;
    bf16_t* woT = wl + 1769472;
    bf16_t* ff1T = wl + 2359296;
    bf16_t* ff2T = wl + 4718592;

    if (l > 0)
      k_ln<<<8192, 192, 0, stream>>>(x, h, ln1_s + l * 768, ln1_b + l * 768);
    if (!big) {
      k_convT3<<<dim3(2, 24, 36), 256, 0, stream>>>(
          wq + (size_t)l * 589824, wk + (size_t)l * 589824,
          wv + (size_t)l * 589824, qkvT, 589824, 0);
      k_convT<<<dim3(24, 24, 1), 256, 0, stream>>>(wo + (size_t)l * 589824, 0,
                                                   woT, 0, 768, 768);
      k_convT<<<dim3(96, 24, 1), 256, 0, stream>>>(ff1w + (size_t)l * 2359296,
                                                   0, ff1T, 0, 3072, 768);
      k_convT<<<dim3(24, 96, 1), 256, 0, stream>>>(ff2w + (size_t)l * 2359296,
                                                   0, ff2T, 0, 768, 3072);
    }
    // QKV: M=8192 N=2304 K=768 -> grid 18*64=1152
    k_gemm<0><<<1152, 256, 0, stream>>>(h, 768, qkvT, 768, 768,
                                        nullptr, qkv, 2304, nullptr, 18);
    // attention (log-softmax decomposition)
    k_lse<<<dim3(192, 8), 256, 0, stream>>>(qkv, lseb);
    k_attn2<<<192, 256, 0, stream>>>(qkv, lseb, ctx);
    // WO + residual: grid 6*64=384
    k_gemm<1><<<384, 256, 0, stream>>>(ctx, 768, woT, 768, 768, x,
                                       nullptr, 768, wo_b + l * 768, 6);
    // FFN
    k_ln<<<8192, 192, 0, stream>>>(x, h, ln2_s + l * 768, ln2_b + l * 768);
    // FF1: grid 24*64=1536
    k_gemm<2><<<1536, 256, 0, stream>>>(h, 768, ff1T, 768, 768,
                                        nullptr, gbuf, 3072,
                                        ff1b + l * 3072, 24);
    // FF2: grid 6*64=384
    k_gemm<1><<<384, 256, 0, stream>>>(gbuf, 3072, ff2T, 3072, 3072, x,
                                       nullptr, 768, ff2b + l * 768, 6);
  }
  k_final<<<16, 192, 0, stream>>>(x, fln_s, fln_b, cw, cb, out);
}